// Round 6
// baseline (218.343 us; speedup 1.0000x reference)
//
#include <hip/hip_runtime.h>
#include <hip/hip_bf16.h>

#define S 4096
#define DM 512
#define HH 8
#define DK 64
#define MT 8192     // B*S
#define KVB 64

typedef __attribute__((ext_vector_type(8))) short bf16x8;
typedef __attribute__((ext_vector_type(4))) float f32x4;

#define CQ 0.18033688011112042f   // 0.125 * log2(e), folded into Q projection

__device__ __forceinline__ short f2bs(float x) {
    __hip_bfloat16 h = __float2bfloat16(x);
    return *reinterpret_cast<short*>(&h);
}

__device__ __forceinline__ bf16x8 pack8(const float4& a, const float4& b) {
    bf16x8 r;
    r[0] = f2bs(a.x); r[1] = f2bs(a.y); r[2] = f2bs(a.z); r[3] = f2bs(a.w);
    r[4] = f2bs(b.x); r[5] = f2bs(b.y); r[6] = f2bs(b.z); r[7] = f2bs(b.w);
    return r;
}

// ---------------- Fused QKV projection ----------------
// BM=128 BN=64 BK=64, 4 waves (2Mx2N). blockIdx.x: [0..7]=Q, [8..15]=K, [16..23]=V.
// Q/K write bf16 [bh][s][d] (Q pre-scaled by CQ); V writes bf16 [bh][d][s].
__global__ __launch_bounds__(256, 4)
void qkv_gemm(const float* __restrict__ Xq, const float* __restrict__ Xk,
              const float* __restrict__ Xv,
              const float* __restrict__ Wq, const float* __restrict__ Wk,
              const float* __restrict__ Wv,
              const float* __restrict__ Bq, const float* __restrict__ Bk,
              const float* __restrict__ Bv,
              unsigned short* __restrict__ Yq, unsigned short* __restrict__ Yk,
              unsigned short* __restrict__ Yv)
{
    __shared__ char As[128 * 128];
    __shared__ char Bs[64 * 128];
    const int mat = blockIdx.x >> 3;
    const int n0  = (blockIdx.x & 7) * 64;
    const int m0  = blockIdx.y * 128;
    const float* X    = mat == 0 ? Xq : (mat == 1 ? Xk : Xv);
    const float* W    = mat == 0 ? Wq : (mat == 1 ? Wk : Wv);
    const float* bias = mat == 0 ? Bq : (mat == 1 ? Bk : Bv);

    const int t = threadIdx.x, l = t & 63, w = t >> 6;
    const int wr = w >> 1, wc = w & 1;
    const int lr = l & 15, lg = l >> 4;
    const int srow = t >> 3, schk = t & 7;
    const int sswz = (schk ^ (srow & 7)) * 16;

    float4 fA[4][2]; float4 fB[2][2];
    auto loadA = [&](int k0) {
        #pragma unroll
        for (int i = 0; i < 4; ++i) {
            const float* p = X + (size_t)(m0 + srow + 32 * i) * DM + k0 + schk * 8;
            fA[i][0] = *(const float4*)p;
            fA[i][1] = *(const float4*)(p + 4);
        }
    };
    auto loadB = [&](int k0) {
        #pragma unroll
        for (int i = 0; i < 2; ++i) {
            const float* p = W + (size_t)(n0 + srow + 32 * i) * DM + k0 + schk * 8;
            fB[i][0] = *(const float4*)p;
            fB[i][1] = *(const float4*)(p + 4);
        }
    };

    loadA(0); loadB(0);

    f32x4 acc[4][2];
    #pragma unroll
    for (int fm = 0; fm < 4; ++fm)
        #pragma unroll
        for (int fn = 0; fn < 2; ++fn) acc[fm][fn] = f32x4{0.f, 0.f, 0.f, 0.f};

    #pragma unroll
    for (int kt = 0; kt < 8; ++kt) {
        bf16x8 wA[4], wB[2];
        #pragma unroll
        for (int i = 0; i < 4; ++i) wA[i] = pack8(fA[i][0], fA[i][1]);
        #pragma unroll
        for (int i = 0; i < 2; ++i) wB[i] = pack8(fB[i][0], fB[i][1]);

        if (kt < 7) { loadA((kt + 1) * 64); loadB((kt + 1) * 64); }

        __syncthreads();
        #pragma unroll
        for (int i = 0; i < 4; ++i)
            *(bf16x8*)(As + (srow + 32 * i) * 128 + sswz) = wA[i];
        #pragma unroll
        for (int i = 0; i < 2; ++i)
            *(bf16x8*)(Bs + (srow + 32 * i) * 128 + sswz) = wB[i];
        __syncthreads();

        #pragma unroll
        for (int kc = 0; kc < 2; ++kc) {
            bf16x8 af[4], bfr[2];
            #pragma unroll
            for (int fm = 0; fm < 4; ++fm) {
                int row = wr * 64 + fm * 16 + lr;
                af[fm] = *(const bf16x8*)(As + row * 128 + (((kc * 4 + lg) ^ (row & 7)) * 16));
            }
            #pragma unroll
            for (int fn = 0; fn < 2; ++fn) {
                int row = wc * 32 + fn * 16 + lr;
                bfr[fn] = *(const bf16x8*)(Bs + row * 128 + (((kc * 4 + lg) ^ (row & 7)) * 16));
            }
            #pragma unroll
            for (int fm = 0; fm < 4; ++fm)
                #pragma unroll
                for (int fn = 0; fn < 2; ++fn)
                    acc[fm][fn] = __builtin_amdgcn_mfma_f32_16x16x32_bf16(af[fm], bfr[fn], acc[fm][fn], 0, 0, 0);
        }
    }

    const float scale = (mat == 0) ? CQ : 1.0f;
    #pragma unroll
    for (int fm = 0; fm < 4; ++fm) {
        #pragma unroll
        for (int fn = 0; fn < 2; ++fn) {
            int n = n0 + wc * 32 + fn * 16 + lr;
            float bn = bias[n];
            int mbase = m0 + wr * 64 + fm * 16 + lg * 4;
            int h = n >> 6, d = n & 63;
            if (mat < 2) {
                unsigned short* Y = (mat == 0) ? Yq : Yk;
                #pragma unroll
                for (int r = 0; r < 4; ++r) {
                    int m = mbase + r, b = m >> 12, s = m & (S - 1);
                    Y[(((size_t)(b * HH + h)) * S + s) * DK + d] =
                        (unsigned short)f2bs((acc[fm][fn][r] + bn) * scale);
                }
            } else {
                int b = mbase >> 12, s = mbase & (S - 1);
                ushort4 u;
                u.x = (unsigned short)f2bs(acc[fm][fn][0] + bn);
                u.y = (unsigned short)f2bs(acc[fm][fn][1] + bn);
                u.z = (unsigned short)f2bs(acc[fm][fn][2] + bn);
                u.w = (unsigned short)f2bs(acc[fm][fn][3] + bn);
                *(ushort4*)(Yv + ((size_t)((b * HH + h) * DK + d)) * S + s) = u;
            }
        }
    }
}

// ---------------- Output projection (bf16 X, f32 out) ----------------
__global__ __launch_bounds__(256, 2)
void out_gemm(const short* __restrict__ Xb, const float* __restrict__ W,
              const float* __restrict__ bias, float* __restrict__ Y)
{
    __shared__ char As[128 * 128];
    __shared__ char Bs[64 * 128];
    const int t = threadIdx.x, l = t & 63, w = t >> 6;
    const int wr = w >> 1, wc = w & 1;
    const int m0 = blockIdx.y * 128, n0 = blockIdx.x * 64;
    const int lr = l & 15, lg = l >> 4;
    const int srow = t >> 3, schk = t & 7;
    const int sswz = (schk ^ (srow & 7)) * 16;

    float4 fB[2][2]; bf16x8 rA[4];
    auto loadA = [&](int k0) {
        #pragma unroll
        for (int i = 0; i < 4; ++i)
            rA[i] = *(const bf16x8*)(Xb + (size_t)(m0 + srow + 32 * i) * DM + k0 + schk * 8);
    };
    auto loadB = [&](int k0) {
        #pragma unroll
        for (int i = 0; i < 2; ++i) {
            const float* p = W + (size_t)(n0 + srow + 32 * i) * DM + k0 + schk * 8;
            fB[i][0] = *(const float4*)p;
            fB[i][1] = *(const float4*)(p + 4);
        }
    };

    loadA(0); loadB(0);

    f32x4 acc[4][2];
    #pragma unroll
    for (int fm = 0; fm < 4; ++fm)
        #pragma unroll
        for (int fn = 0; fn < 2; ++fn) acc[fm][fn] = f32x4{0.f, 0.f, 0.f, 0.f};

    #pragma unroll
    for (int kt = 0; kt < 8; ++kt) {
        bf16x8 wA[4], wB[2];
        #pragma unroll
        for (int i = 0; i < 4; ++i) wA[i] = rA[i];
        #pragma unroll
        for (int i = 0; i < 2; ++i) wB[i] = pack8(fB[i][0], fB[i][1]);

        if (kt < 7) { loadA((kt + 1) * 64); loadB((kt + 1) * 64); }

        __syncthreads();
        #pragma unroll
        for (int i = 0; i < 4; ++i)
            *(bf16x8*)(As + (srow + 32 * i) * 128 + sswz) = wA[i];
        #pragma unroll
        for (int i = 0; i < 2; ++i)
            *(bf16x8*)(Bs + (srow + 32 * i) * 128 + sswz) = wB[i];
        __syncthreads();

        #pragma unroll
        for (int kc = 0; kc < 2; ++kc) {
            bf16x8 af[4], bfr[2];
            #pragma unroll
            for (int fm = 0; fm < 4; ++fm) {
                int row = wr * 64 + fm * 16 + lr;
                af[fm] = *(const bf16x8*)(As + row * 128 + (((kc * 4 + lg) ^ (row & 7)) * 16));
            }
            #pragma unroll
            for (int fn = 0; fn < 2; ++fn) {
                int row = wc * 32 + fn * 16 + lr;
                bfr[fn] = *(const bf16x8*)(Bs + row * 128 + (((kc * 4 + lg) ^ (row & 7)) * 16));
            }
            #pragma unroll
            for (int fm = 0; fm < 4; ++fm)
                #pragma unroll
                for (int fn = 0; fn < 2; ++fn)
                    acc[fm][fn] = __builtin_amdgcn_mfma_f32_16x16x32_bf16(af[fm], bfr[fn], acc[fm][fn], 0, 0, 0);
        }
    }

    #pragma unroll
    for (int fm = 0; fm < 4; ++fm) {
        #pragma unroll
        for (int fn = 0; fn < 2; ++fn) {
            int n = n0 + wc * 32 + fn * 16 + lr;
            float bn = bias[n];
            int mbase = m0 + wr * 64 + fm * 16 + lg * 4;
            #pragma unroll
            for (int r = 0; r < 4; ++r)
                Y[(size_t)(mbase + r) * DM + n] = acc[fm][fn][r] + bn;
        }
    }
}

// ---------------- Flash attention: 32 q/wave, swapped QK^T, swizzled P ------
// qh: bf16 [bh][s][64] PRE-SCALED by 0.125*log2(e); kh: bf16 [bh][s][64];
// vt: bf16 [bh][64][s]; att: bf16 [b*S+s][DM].
// Each wave owns 32 queries (2 x 16); K/V fragment reads amortized over both.
// P per wave: 32 rows x 128B, chunk-XOR swizzled by (lr&7).
__global__ __launch_bounds__(256, 2)
void flash_mfma(const __hip_bfloat16* __restrict__ qh,
                const __hip_bfloat16* __restrict__ kh,
                const __hip_bfloat16* __restrict__ vt,
                const int* __restrict__ mask,
                __hip_bfloat16* __restrict__ att)
{
    const int bh = blockIdx.y, b = bh >> 3, h = bh & 7;
    const int q0 = blockIdx.x * 128;
    const int t = threadIdx.x, w = t >> 6, l = t & 63;
    const int lr = l & 15, lg = l >> 4;

    __shared__ char  KsB[8192];      // K tile [64 key][64 d], 16B-chunk XOR swz
    __shared__ char  VsB[8192];      // V^T tile [64 d][64 key], same swz
    __shared__ char  PlB[4 * 4096];  // per-wave P [32 q][64 key] bf16, swizzled
    __shared__ float mskf[KVB];

    const short* qg = (const short*)qh + ((size_t)bh * S + q0 + w * 32) * DK;
    bf16x8 qf[2][2];
    #pragma unroll
    for (int qt = 0; qt < 2; ++qt)
        #pragma unroll
        for (int kc = 0; kc < 2; ++kc)
            qf[qt][kc] = *(const bf16x8*)(qg + (qt * 16 + lr) * DK + kc * 32 + lg * 8);

    f32x4 o[2][4];
    float lsum[2] = {0.f, 0.f};
    #pragma unroll
    for (int qt = 0; qt < 2; ++qt)
        #pragma unroll
        for (int dt = 0; dt < 4; ++dt) o[qt][dt] = f32x4{0.f, 0.f, 0.f, 0.f};

    const short* kgb = (const short*)kh + (size_t)bh * S * DK;
    const short* vgb = (const short*)vt + (size_t)bh * DK * S;
    const int*   mb  = mask + b * S;

    char* Pw = PlB + w * 4096;

    const int sr = t >> 2, c2 = (t & 3) * 2;
    const int swz = (sr & 7) << 4;

    bf16x8 rK0, rK1, rV0, rV1;
    float  mreg = 0.f;

    auto issue = [&](int kt) {
        rK0 = *(const bf16x8*)(kgb + (size_t)(kt + sr) * DK + c2 * 8);
        rK1 = *(const bf16x8*)(kgb + (size_t)(kt + sr) * DK + c2 * 8 + 8);
        rV0 = *(const bf16x8*)(vgb + (size_t)sr * S + kt + c2 * 8);
        rV1 = *(const bf16x8*)(vgb + (size_t)sr * S + kt + c2 * 8 + 8);
        if (t < KVB) mreg = (float)mb[kt + t];
    };

    issue(0);

    for (int kt = 0; kt < S; kt += KVB) {
        __syncthreads();
        *(bf16x8*)(KsB + sr * 128 + ((c2 * 16) ^ swz))       = rK0;
        *(bf16x8*)(KsB + sr * 128 + (((c2 + 1) * 16) ^ swz)) = rK1;
        *(bf16x8*)(VsB + sr * 128 + ((c2 * 16) ^ swz))       = rV0;
        *(bf16x8*)(VsB + sr * 128 + (((c2 + 1) * 16) ^ swz)) = rV1;
        if (t < KVB) mskf[t] = mreg;
        __syncthreads();
        if (kt + KVB < S) issue(kt + KVB);

        // ---- QK^T (swapped): scf[qt][kkt] regs = keys 4lg+r (+16kkt), col = q lr
        f32x4 scf[2][4];
        #pragma unroll
        for (int qt = 0; qt < 2; ++qt)
            #pragma unroll
            for (int kkt = 0; kkt < 4; ++kkt) scf[qt][kkt] = f32x4{0.f, 0.f, 0.f, 0.f};
        #pragma unroll
        for (int kc = 0; kc < 2; ++kc)
            #pragma unroll
            for (int kkt = 0; kkt < 4; ++kkt) {
                int row = kkt * 16 + lr;
                bf16x8 kf = *(const bf16x8*)(KsB + row * 128 +
                                 ((kc * 64 + lg * 16) ^ ((row & 7) << 4)));
                scf[0][kkt] = __builtin_amdgcn_mfma_f32_16x16x32_bf16(kf, qf[0][kc], scf[0][kkt], 0, 0, 0);
                scf[1][kkt] = __builtin_amdgcn_mfma_f32_16x16x32_bf16(kf, qf[1][kc], scf[1][kkt], 0, 0, 0);
            }

        // ---- unnormalized softmax; swizzled packed 8B P writes
        #pragma unroll
        for (int qt = 0; qt < 2; ++qt)
            #pragma unroll
            for (int kkt = 0; kkt < 4; ++kkt) {
                f32x4 mf4 = *(const f32x4*)&mskf[kkt * 16 + lg * 4];
                float p0 = mf4[0] * exp2f(scf[qt][kkt][0]);
                float p1 = mf4[1] * exp2f(scf[qt][kkt][1]);
                float p2 = mf4[2] * exp2f(scf[qt][kkt][2]);
                float p3 = mf4[3] * exp2f(scf[qt][kkt][3]);
                lsum[qt] += (p0 + p1) + (p2 + p3);
                ushort4 u;
                u.x = (unsigned short)f2bs(p0);
                u.y = (unsigned short)f2bs(p1);
                u.z = (unsigned short)f2bs(p2);
                u.w = (unsigned short)f2bs(p3);
                *(ushort4*)(Pw + (qt * 16 + lr) * 128 +
                            (((kkt * 2 + (lg >> 1)) ^ (lr & 7)) * 16) + (lg & 1) * 8) = u;
            }

        // ---- PV: O += P @ V (V frags shared across qt)
        #pragma unroll
        for (int kc = 0; kc < 2; ++kc) {
            bf16x8 pf0 = *(const bf16x8*)(Pw + lr * 128 + (((kc * 4 + lg) ^ (lr & 7)) * 16));
            bf16x8 pf1 = *(const bf16x8*)(Pw + (16 + lr) * 128 + (((kc * 4 + lg) ^ (lr & 7)) * 16));
            #pragma unroll
            for (int dt = 0; dt < 4; ++dt) {
                int row = dt * 16 + lr;
                bf16x8 vf = *(const bf16x8*)(VsB + row * 128 +
                                 ((kc * 64 + lg * 16) ^ ((row & 7) << 4)));
                o[0][dt] = __builtin_amdgcn_mfma_f32_16x16x32_bf16(pf0, vf, o[0][dt], 0, 0, 0);
                o[1][dt] = __builtin_amdgcn_mfma_f32_16x16x32_bf16(pf1, vf, o[1][dt], 0, 0, 0);
            }
        }
    }

    // ---- epilogue: l lives per-query at lane lr; redistribute to O rows
    const size_t ob = (size_t)(b * S + q0 + w * 32) * DM + h * DK;
    #pragma unroll
    for (int qt = 0; qt < 2; ++qt) {
        float ls = lsum[qt];
        ls += __shfl_xor(ls, 16);
        ls += __shfl_xor(ls, 32);
        f32x4 linv;
        #pragma unroll
        for (int r = 0; r < 4; ++r)
            linv[r] = 1.0f / __shfl(ls, lg * 4 + r);
        #pragma unroll
        for (int dt = 0; dt < 4; ++dt) {
            #pragma unroll
            for (int r = 0; r < 4; ++r)
                att[ob + (size_t)(qt * 16 + 4 * lg + r) * DM + dt * 16 + lr] =
                    __float2bfloat16(o[qt][dt][r] * linv[r]);
        }
    }
}

extern "C" void kernel_launch(void* const* d_in, const int* in_sizes, int n_in,
                              void* d_out, int out_size, void* d_ws, size_t ws_size,
                              hipStream_t stream) {
    const float* q    = (const float*)d_in[0];
    const float* k    = (const float*)d_in[1];
    const float* v    = (const float*)d_in[2];
    const int*   mask = (const int*)  d_in[3];
    const float* wq   = (const float*)d_in[4];
    const float* bq   = (const float*)d_in[5];
    const float* wk   = (const float*)d_in[6];
    const float* bk   = (const float*)d_in[7];
    const float* wv   = (const float*)d_in[8];
    const float* bv   = (const float*)d_in[9];
    const float* wo   = (const float*)d_in[10];
    const float* bo   = (const float*)d_in[11];
    float* out = (float*)d_out;

    char* wsb = (char*)d_ws;
    __hip_bfloat16* qh  = (__hip_bfloat16*)(wsb);
    __hip_bfloat16* kh  = (__hip_bfloat16*)(wsb + (size_t)8  * 1024 * 1024);
    __hip_bfloat16* vt  = (__hip_bfloat16*)(wsb + (size_t)16 * 1024 * 1024);
    __hip_bfloat16* att = (__hip_bfloat16*)(wsb + (size_t)24 * 1024 * 1024);

    dim3 blk(256);
    dim3 gq(24, MT / 128);                 // fused QKV: 1536 blocks
    qkv_gemm<<<gq, blk, 0, stream>>>(q, k, v, wq, wk, wv, bq, bk, bv,
                                     (unsigned short*)qh, (unsigned short*)kh,
                                     (unsigned short*)vt);

    dim3 g2(S / 128, 16);                  // 512 blocks, 32 q/wave
    flash_mfma<<<g2, blk, 0, stream>>>(qh, kh, vt, mask, att);

    dim3 gg(DM / 64, MT / 128);            // (8, 64)
    out_gemm<<<gg, blk, 0, stream>>>((const short*)att, wo, bo, out);
}

// Round 7
// 217.340 us; speedup vs baseline: 1.0046x; 1.0046x over previous
//
#include <hip/hip_runtime.h>
#include <hip/hip_bf16.h>

#define S 4096
#define DM 512
#define HH 8
#define DK 64
#define MT 8192     // B*S
#define KVB 64

typedef __attribute__((ext_vector_type(8)))  short bf16x8;
typedef __attribute__((ext_vector_type(4)))  float f32x4;
typedef __attribute__((ext_vector_type(16))) float f32x16;
typedef __attribute__((ext_vector_type(4)))  unsigned int u32x4;

#define CQ 0.18033688011112042f   // 0.125 * log2(e), folded into Q projection

__device__ __forceinline__ short f2bs(float x) {
    __hip_bfloat16 h = __float2bfloat16(x);
    return *reinterpret_cast<short*>(&h);
}

__device__ __forceinline__ bf16x8 pack8(const float4& a, const float4& b) {
    bf16x8 r;
    r[0] = f2bs(a.x); r[1] = f2bs(a.y); r[2] = f2bs(a.z); r[3] = f2bs(a.w);
    r[4] = f2bs(b.x); r[5] = f2bs(b.y); r[6] = f2bs(b.z); r[7] = f2bs(b.w);
    return r;
}

__device__ __forceinline__ unsigned cvtpk(float lo, float hi) {
    unsigned r;
    asm("v_cvt_pk_bf16_f32 %0, %1, %2" : "=v"(r) : "v"(lo), "v"(hi));
    return r;
}

__device__ __forceinline__ bf16x8 mk_pb(unsigned a, unsigned b, unsigned c, unsigned d) {
    u32x4 t; t[0] = a; t[1] = b; t[2] = c; t[3] = d;
    return __builtin_bit_cast(bf16x8, t);
}

// ---------------- Fused QKV projection (unchanged from R6) ----------------
__global__ __launch_bounds__(256, 4)
void qkv_gemm(const float* __restrict__ Xq, const float* __restrict__ Xk,
              const float* __restrict__ Xv,
              const float* __restrict__ Wq, const float* __restrict__ Wk,
              const float* __restrict__ Wv,
              const float* __restrict__ Bq, const float* __restrict__ Bk,
              const float* __restrict__ Bv,
              unsigned short* __restrict__ Yq, unsigned short* __restrict__ Yk,
              unsigned short* __restrict__ Yv)
{
    __shared__ char As[128 * 128];
    __shared__ char Bs[64 * 128];
    const int mat = blockIdx.x >> 3;
    const int n0  = (blockIdx.x & 7) * 64;
    const int m0  = blockIdx.y * 128;
    const float* X    = mat == 0 ? Xq : (mat == 1 ? Xk : Xv);
    const float* W    = mat == 0 ? Wq : (mat == 1 ? Wk : Wv);
    const float* bias = mat == 0 ? Bq : (mat == 1 ? Bk : Bv);

    const int t = threadIdx.x, l = t & 63, w = t >> 6;
    const int wr = w >> 1, wc = w & 1;
    const int lr = l & 15, lg = l >> 4;
    const int srow = t >> 3, schk = t & 7;
    const int sswz = (schk ^ (srow & 7)) * 16;

    float4 fA[4][2]; float4 fB[2][2];
    auto loadA = [&](int k0) {
        #pragma unroll
        for (int i = 0; i < 4; ++i) {
            const float* p = X + (size_t)(m0 + srow + 32 * i) * DM + k0 + schk * 8;
            fA[i][0] = *(const float4*)p;
            fA[i][1] = *(const float4*)(p + 4);
        }
    };
    auto loadB = [&](int k0) {
        #pragma unroll
        for (int i = 0; i < 2; ++i) {
            const float* p = W + (size_t)(n0 + srow + 32 * i) * DM + k0 + schk * 8;
            fB[i][0] = *(const float4*)p;
            fB[i][1] = *(const float4*)(p + 4);
        }
    };

    loadA(0); loadB(0);

    f32x4 acc[4][2];
    #pragma unroll
    for (int fm = 0; fm < 4; ++fm)
        #pragma unroll
        for (int fn = 0; fn < 2; ++fn) acc[fm][fn] = f32x4{0.f, 0.f, 0.f, 0.f};

    #pragma unroll
    for (int kt = 0; kt < 8; ++kt) {
        bf16x8 wA[4], wB[2];
        #pragma unroll
        for (int i = 0; i < 4; ++i) wA[i] = pack8(fA[i][0], fA[i][1]);
        #pragma unroll
        for (int i = 0; i < 2; ++i) wB[i] = pack8(fB[i][0], fB[i][1]);

        if (kt < 7) { loadA((kt + 1) * 64); loadB((kt + 1) * 64); }

        __syncthreads();
        #pragma unroll
        for (int i = 0; i < 4; ++i)
            *(bf16x8*)(As + (srow + 32 * i) * 128 + sswz) = wA[i];
        #pragma unroll
        for (int i = 0; i < 2; ++i)
            *(bf16x8*)(Bs + (srow + 32 * i) * 128 + sswz) = wB[i];
        __syncthreads();

        #pragma unroll
        for (int kc = 0; kc < 2; ++kc) {
            bf16x8 af[4], bfr[2];
            #pragma unroll
            for (int fm = 0; fm < 4; ++fm) {
                int row = wr * 64 + fm * 16 + lr;
                af[fm] = *(const bf16x8*)(As + row * 128 + (((kc * 4 + lg) ^ (row & 7)) * 16));
            }
            #pragma unroll
            for (int fn = 0; fn < 2; ++fn) {
                int row = wc * 32 + fn * 16 + lr;
                bfr[fn] = *(const bf16x8*)(Bs + row * 128 + (((kc * 4 + lg) ^ (row & 7)) * 16));
            }
            #pragma unroll
            for (int fm = 0; fm < 4; ++fm)
                #pragma unroll
                for (int fn = 0; fn < 2; ++fn)
                    acc[fm][fn] = __builtin_amdgcn_mfma_f32_16x16x32_bf16(af[fm], bfr[fn], acc[fm][fn], 0, 0, 0);
        }
    }

    const float scale = (mat == 0) ? CQ : 1.0f;
    #pragma unroll
    for (int fm = 0; fm < 4; ++fm) {
        #pragma unroll
        for (int fn = 0; fn < 2; ++fn) {
            int n = n0 + wc * 32 + fn * 16 + lr;
            float bn = bias[n];
            int mbase = m0 + wr * 64 + fm * 16 + lg * 4;
            int h = n >> 6, d = n & 63;
            if (mat < 2) {
                unsigned short* Y = (mat == 0) ? Yq : Yk;
                #pragma unroll
                for (int r = 0; r < 4; ++r) {
                    int m = mbase + r, b = m >> 12, s = m & (S - 1);
                    Y[(((size_t)(b * HH + h)) * S + s) * DK + d] =
                        (unsigned short)f2bs((acc[fm][fn][r] + bn) * scale);
                }
            } else {
                int b = mbase >> 12, s = mbase & (S - 1);
                ushort4 u;
                u.x = (unsigned short)f2bs(acc[fm][fn][0] + bn);
                u.y = (unsigned short)f2bs(acc[fm][fn][1] + bn);
                u.z = (unsigned short)f2bs(acc[fm][fn][2] + bn);
                u.w = (unsigned short)f2bs(acc[fm][fn][3] + bn);
                *(ushort4*)(Yv + ((size_t)((b * HH + h) * DK + d)) * S + s) = u;
            }
        }
    }
}

// ---------------- Output projection (unchanged from R6) ----------------
__global__ __launch_bounds__(256, 2)
void out_gemm(const short* __restrict__ Xb, const float* __restrict__ W,
              const float* __restrict__ bias, float* __restrict__ Y)
{
    __shared__ char As[128 * 128];
    __shared__ char Bs[64 * 128];
    const int t = threadIdx.x, l = t & 63, w = t >> 6;
    const int wr = w >> 1, wc = w & 1;
    const int m0 = blockIdx.y * 128, n0 = blockIdx.x * 64;
    const int lr = l & 15, lg = l >> 4;
    const int srow = t >> 3, schk = t & 7;
    const int sswz = (schk ^ (srow & 7)) * 16;

    float4 fB[2][2]; bf16x8 rA[4];
    auto loadA = [&](int k0) {
        #pragma unroll
        for (int i = 0; i < 4; ++i)
            rA[i] = *(const bf16x8*)(Xb + (size_t)(m0 + srow + 32 * i) * DM + k0 + schk * 8);
    };
    auto loadB = [&](int k0) {
        #pragma unroll
        for (int i = 0; i < 2; ++i) {
            const float* p = W + (size_t)(n0 + srow + 32 * i) * DM + k0 + schk * 8;
            fB[i][0] = *(const float4*)p;
            fB[i][1] = *(const float4*)(p + 4);
        }
    };

    loadA(0); loadB(0);

    f32x4 acc[4][2];
    #pragma unroll
    for (int fm = 0; fm < 4; ++fm)
        #pragma unroll
        for (int fn = 0; fn < 2; ++fn) acc[fm][fn] = f32x4{0.f, 0.f, 0.f, 0.f};

    #pragma unroll
    for (int kt = 0; kt < 8; ++kt) {
        bf16x8 wA[4], wB[2];
        #pragma unroll
        for (int i = 0; i < 4; ++i) wA[i] = rA[i];
        #pragma unroll
        for (int i = 0; i < 2; ++i) wB[i] = pack8(fB[i][0], fB[i][1]);

        if (kt < 7) { loadA((kt + 1) * 64); loadB((kt + 1) * 64); }

        __syncthreads();
        #pragma unroll
        for (int i = 0; i < 4; ++i)
            *(bf16x8*)(As + (srow + 32 * i) * 128 + sswz) = wA[i];
        #pragma unroll
        for (int i = 0; i < 2; ++i)
            *(bf16x8*)(Bs + (srow + 32 * i) * 128 + sswz) = wB[i];
        __syncthreads();

        #pragma unroll
        for (int kc = 0; kc < 2; ++kc) {
            bf16x8 af[4], bfr[2];
            #pragma unroll
            for (int fm = 0; fm < 4; ++fm) {
                int row = wr * 64 + fm * 16 + lr;
                af[fm] = *(const bf16x8*)(As + row * 128 + (((kc * 4 + lg) ^ (row & 7)) * 16));
            }
            #pragma unroll
            for (int fn = 0; fn < 2; ++fn) {
                int row = wc * 32 + fn * 16 + lr;
                bfr[fn] = *(const bf16x8*)(Bs + row * 128 + (((kc * 4 + lg) ^ (row & 7)) * 16));
            }
            #pragma unroll
            for (int fm = 0; fm < 4; ++fm)
                #pragma unroll
                for (int fn = 0; fn < 2; ++fn)
                    acc[fm][fn] = __builtin_amdgcn_mfma_f32_16x16x32_bf16(af[fm], bfr[fn], acc[fm][fn], 0, 0, 0);
        }
    }

    #pragma unroll
    for (int fm = 0; fm < 4; ++fm) {
        #pragma unroll
        for (int fn = 0; fn < 2; ++fn) {
            int n = n0 + wc * 32 + fn * 16 + lr;
            float bn = bias[n];
            int mbase = m0 + wr * 64 + fm * 16 + lg * 4;
            #pragma unroll
            for (int r = 0; r < 4; ++r)
                Y[(size_t)(mbase + r) * DM + n] = acc[fm][fn][r] + bn;
        }
    }
}

// ---------------- Flash attention: 32x32 MFMA, in-register P ----------------
// qh: bf16 [bh][s][64] PRE-SCALED by CQ; kh: bf16 [bh][s][64]; vt: bf16 [bh][64][s].
// 2 waves/block, 32 q/wave. Swapped QK^T (mfma(K,Q)) -> C[key][query=l&31];
// P redistributed to PV B-frags via v_cvt_pk_bf16_f32 + v_permlane32_swap_b32
// (no P LDS). PV also swapped: O^T = mfma(V', P). Double-buffered K/V LDS,
// one barrier per tile, reg-staged 2 tiles ahead.
__global__ __launch_bounds__(128, 2)
void flash_mfma(const __hip_bfloat16* __restrict__ qh,
                const __hip_bfloat16* __restrict__ kh,
                const __hip_bfloat16* __restrict__ vt,
                const int* __restrict__ mask,
                __hip_bfloat16* __restrict__ att)
{
    const int bh = blockIdx.y, b = bh >> 3, h = bh & 7;
    const int q0 = blockIdx.x * 64;
    const int t = threadIdx.x, w = t >> 6, l = t & 63;
    const int l31 = l & 31, hi = l >> 5;

    __shared__ char  KsB[2][8192];   // [key 64][dk 64] bf16, 16B-chunk XOR swz
    __shared__ char  VsB[2][8192];   // [d 64][key 64] bf16, same swz
    __shared__ float mskf[2][KVB];

    // Q B-frags in regs: qf[c] = Q[q=l31][dk = c*16 + hi*8 + j]
    const short* qg = (const short*)qh + ((size_t)bh * S + q0 + w * 32 + l31) * DK;
    bf16x8 qf[4];
    #pragma unroll
    for (int c = 0; c < 4; ++c)
        qf[c] = *(const bf16x8*)(qg + c * 16 + hi * 8);

    f32x16 oc[2];
    #pragma unroll
    for (int dt = 0; dt < 2; ++dt)
        #pragma unroll
        for (int r = 0; r < 16; ++r) oc[dt][r] = 0.f;
    float lsum = 0.f;

    const short* kgb = (const short*)kh + (size_t)bh * S * DK;
    const short* vgb = (const short*)vt + (size_t)bh * DK * S;
    const int*   mb  = mask + b * S;

    const int sr = t >> 1, sc4 = (t & 1) * 4;   // staging: row, chunk base (64B/thread/buf)

    bf16x8 rK[4], rV[4];
    float  mreg = 0.f;

    auto issue = [&](int kt) {
        #pragma unroll
        for (int i = 0; i < 4; ++i)
            rK[i] = *(const bf16x8*)(kgb + (size_t)(kt + sr) * DK + (sc4 + i) * 8);
        #pragma unroll
        for (int i = 0; i < 4; ++i)
            rV[i] = *(const bf16x8*)(vgb + (size_t)sr * S + kt + (sc4 + i) * 8);
        if (t < KVB) mreg = (float)mb[kt + t];
    };
    auto stage = [&](int bi) {
        char* kb = KsB[bi]; char* vb = VsB[bi];
        #pragma unroll
        for (int i = 0; i < 4; ++i)
            *(bf16x8*)(kb + sr * 128 + (((sc4 + i) ^ (sr & 7)) * 16)) = rK[i];
        #pragma unroll
        for (int i = 0; i < 4; ++i)
            *(bf16x8*)(vb + sr * 128 + (((sc4 + i) ^ (sr & 7)) * 16)) = rV[i];
        if (t < KVB) mskf[bi][t] = mreg;
    };

    issue(0); stage(0); issue(KVB);

    for (int it = 0; it < S / KVB; ++it) {
        const int cur = it & 1;
        __syncthreads();
        if (it < S / KVB - 1) stage(cur ^ 1);
        if (it < S / KVB - 2) issue((it + 2) * KVB);
        const char*  kb   = KsB[cur];
        const char*  vb   = VsB[cur];
        const float* mskc = mskf[cur];

        #pragma unroll
        for (int st = 0; st < 2; ++st) {
            // ---- QK^T (swapped, 32x32x16): C[key = (r&3)+8(r>>2)+4hi][q = l31]
            f32x16 sc;
            #pragma unroll
            for (int r = 0; r < 16; ++r) sc[r] = 0.f;
            const int krow = st * 32 + l31;
            __builtin_amdgcn_s_setprio(1);
            #pragma unroll
            for (int c = 0; c < 4; ++c) {
                bf16x8 kf = *(const bf16x8*)(kb + krow * 128 +
                                (((c * 2 + hi) ^ (krow & 7)) * 16));
                sc = __builtin_amdgcn_mfma_f32_32x32x16_bf16(kf, qf[c], sc, 0, 0, 0);
            }
            __builtin_amdgcn_s_setprio(0);

            // ---- unnormalized softmax: p = mask * exp2(s)
            float p[16];
            #pragma unroll
            for (int g = 0; g < 4; ++g) {
                f32x4 m4 = *(const f32x4*)(mskc + st * 32 + g * 8 + hi * 4);
                #pragma unroll
                for (int o = 0; o < 4; ++o) {
                    p[g * 4 + o] = m4[o] * exp2f(sc[g * 4 + o]);
                    lsum += p[g * 4 + o];
                }
            }

            // ---- cvt_pk + permlane32_swap -> PV B-frags (in-register)
            unsigned A0 = cvtpk(p[0],  p[1]),  B0 = cvtpk(p[2],  p[3]);
            unsigned A1 = cvtpk(p[4],  p[5]),  B1 = cvtpk(p[6],  p[7]);
            unsigned A2 = cvtpk(p[8],  p[9]),  B2 = cvtpk(p[10], p[11]);
            unsigned A3 = cvtpk(p[12], p[13]), B3 = cvtpk(p[14], p[15]);
            asm("v_permlane32_swap_b32 %0, %1" : "+v"(A0), "+v"(A1));
            asm("v_permlane32_swap_b32 %0, %1" : "+v"(B0), "+v"(B1));
            asm("v_permlane32_swap_b32 %0, %1" : "+v"(A2), "+v"(A3));
            asm("v_permlane32_swap_b32 %0, %1" : "+v"(B2), "+v"(B3));
            // after swap: A0 = keys {hi*8+0,+1}, B0 = {+2,+3}, A1 = {+4,+5}, B1 = {+6,+7}  (kcl 0)
            bf16x8 pb0 = mk_pb(A0, B0, A1, B1);
            bf16x8 pb1 = mk_pb(A2, B2, A3, B3);

            // ---- PV (swapped): oc[dt] += mfma(V', P), C[d][q = l31]
            __builtin_amdgcn_s_setprio(1);
            #pragma unroll
            for (int kcl = 0; kcl < 2; ++kcl) {
                const bf16x8 pb = kcl ? pb1 : pb0;
                const int kc = st * 2 + kcl;
                #pragma unroll
                for (int dt = 0; dt < 2; ++dt) {
                    const int vrow = dt * 32 + l31;
                    bf16x8 vf = *(const bf16x8*)(vb + vrow * 128 +
                                    (((kc * 2 + hi) ^ (vrow & 7)) * 16));
                    oc[dt] = __builtin_amdgcn_mfma_f32_32x32x16_bf16(vf, pb, oc[dt], 0, 0, 0);
                }
            }
            __builtin_amdgcn_s_setprio(0);
        }
    }

    // ---- epilogue: l is per-lane (query l31); combine halves, normalize, write
    lsum += __shfl_xor(lsum, 32);
    const float linv = 1.0f / lsum;
    const int q = q0 + w * 32 + l31;
    unsigned short* ap = (unsigned short*)att + ((size_t)(b * S + q)) * DM + h * DK;
    #pragma unroll
    for (int dt = 0; dt < 2; ++dt)
        #pragma unroll
        for (int g = 0; g < 4; ++g) {
            unsigned lo  = cvtpk(oc[dt][g * 4 + 0] * linv, oc[dt][g * 4 + 1] * linv);
            unsigned hi2 = cvtpk(oc[dt][g * 4 + 2] * linv, oc[dt][g * 4 + 3] * linv);
            uint2 u; u.x = lo; u.y = hi2;
            *(uint2*)(ap + dt * 32 + g * 8 + hi * 4) = u;
        }
}

extern "C" void kernel_launch(void* const* d_in, const int* in_sizes, int n_in,
                              void* d_out, int out_size, void* d_ws, size_t ws_size,
                              hipStream_t stream) {
    const float* q    = (const float*)d_in[0];
    const float* k    = (const float*)d_in[1];
    const float* v    = (const float*)d_in[2];
    const int*   mask = (const int*)  d_in[3];
    const float* wq   = (const float*)d_in[4];
    const float* bq   = (const float*)d_in[5];
    const float* wk   = (const float*)d_in[6];
    const float* bk   = (const float*)d_in[7];
    const float* wv   = (const float*)d_in[8];
    const float* bv   = (const float*)d_in[9];
    const float* wo   = (const float*)d_in[10];
    const float* bo   = (const float*)d_in[11];
    float* out = (float*)d_out;

    char* wsb = (char*)d_ws;
    __hip_bfloat16* qh  = (__hip_bfloat16*)(wsb);
    __hip_bfloat16* kh  = (__hip_bfloat16*)(wsb + (size_t)8  * 1024 * 1024);
    __hip_bfloat16* vt  = (__hip_bfloat16*)(wsb + (size_t)16 * 1024 * 1024);
    __hip_bfloat16* att = (__hip_bfloat16*)(wsb + (size_t)24 * 1024 * 1024);

    dim3 blk(256);
    dim3 gq(24, MT / 128);                 // fused QKV: 1536 blocks
    qkv_gemm<<<gq, blk, 0, stream>>>(q, k, v, wq, wk, wv, bq, bk, bv,
                                     (unsigned short*)qh, (unsigned short*)kh,
                                     (unsigned short*)vt);

    dim3 g2(S / 64, 16);                   // 1024 blocks, 128 threads, 32 q/wave
    flash_mfma<<<g2, dim3(128), 0, stream>>>(qh, kh, vt, mask, att);

    dim3 gg(DM / 64, MT / 128);            // (8, 64)
    out_gemm<<<gg, blk, 0, stream>>>((const short*)att, wo, bo, out);
}

// Round 8
// 204.852 us; speedup vs baseline: 1.0659x; 1.0610x over previous
//
#include <hip/hip_runtime.h>
#include <hip/hip_bf16.h>

#define S 4096
#define DM 512
#define HH 8
#define DK 64
#define MT 8192     // B*S
#define KVB 64

typedef __attribute__((ext_vector_type(8)))  short bf16x8;
typedef __attribute__((ext_vector_type(4)))  float f32x4;
typedef __attribute__((ext_vector_type(16))) float f32x16;
typedef __attribute__((ext_vector_type(4)))  unsigned int u32x4;

#define CQ 0.18033688011112042f   // 0.125 * log2(e), folded into Q projection

__device__ __forceinline__ short f2bs(float x) {
    __hip_bfloat16 h = __float2bfloat16(x);
    return *reinterpret_cast<short*>(&h);
}

__device__ __forceinline__ bf16x8 pack8(const float4& a, const float4& b) {
    bf16x8 r;
    r[0] = f2bs(a.x); r[1] = f2bs(a.y); r[2] = f2bs(a.z); r[3] = f2bs(a.w);
    r[4] = f2bs(b.x); r[5] = f2bs(b.y); r[6] = f2bs(b.z); r[7] = f2bs(b.w);
    return r;
}

__device__ __forceinline__ unsigned cvtpk(float lo, float hi) {
    unsigned r;
    asm("v_cvt_pk_bf16_f32 %0, %1, %2" : "=v"(r) : "v"(lo), "v"(hi));
    return r;
}

__device__ __forceinline__ bf16x8 mk_pb(unsigned a, unsigned b, unsigned c, unsigned d) {
    u32x4 t; t[0] = a; t[1] = b; t[2] = c; t[3] = d;
    return __builtin_bit_cast(bf16x8, t);
}

// ---------------- Fused QKV projection (unchanged) ----------------
__global__ __launch_bounds__(256, 4)
void qkv_gemm(const float* __restrict__ Xq, const float* __restrict__ Xk,
              const float* __restrict__ Xv,
              const float* __restrict__ Wq, const float* __restrict__ Wk,
              const float* __restrict__ Wv,
              const float* __restrict__ Bq, const float* __restrict__ Bk,
              const float* __restrict__ Bv,
              unsigned short* __restrict__ Yq, unsigned short* __restrict__ Yk,
              unsigned short* __restrict__ Yv)
{
    __shared__ char As[128 * 128];
    __shared__ char Bs[64 * 128];
    const int mat = blockIdx.x >> 3;
    const int n0  = (blockIdx.x & 7) * 64;
    const int m0  = blockIdx.y * 128;
    const float* X    = mat == 0 ? Xq : (mat == 1 ? Xk : Xv);
    const float* W    = mat == 0 ? Wq : (mat == 1 ? Wk : Wv);
    const float* bias = mat == 0 ? Bq : (mat == 1 ? Bk : Bv);

    const int t = threadIdx.x, l = t & 63, w = t >> 6;
    const int wr = w >> 1, wc = w & 1;
    const int lr = l & 15, lg = l >> 4;
    const int srow = t >> 3, schk = t & 7;
    const int sswz = (schk ^ (srow & 7)) * 16;

    float4 fA[4][2]; float4 fB[2][2];
    auto loadA = [&](int k0) {
        #pragma unroll
        for (int i = 0; i < 4; ++i) {
            const float* p = X + (size_t)(m0 + srow + 32 * i) * DM + k0 + schk * 8;
            fA[i][0] = *(const float4*)p;
            fA[i][1] = *(const float4*)(p + 4);
        }
    };
    auto loadB = [&](int k0) {
        #pragma unroll
        for (int i = 0; i < 2; ++i) {
            const float* p = W + (size_t)(n0 + srow + 32 * i) * DM + k0 + schk * 8;
            fB[i][0] = *(const float4*)p;
            fB[i][1] = *(const float4*)(p + 4);
        }
    };

    loadA(0); loadB(0);

    f32x4 acc[4][2];
    #pragma unroll
    for (int fm = 0; fm < 4; ++fm)
        #pragma unroll
        for (int fn = 0; fn < 2; ++fn) acc[fm][fn] = f32x4{0.f, 0.f, 0.f, 0.f};

    #pragma unroll
    for (int kt = 0; kt < 8; ++kt) {
        bf16x8 wA[4], wB[2];
        #pragma unroll
        for (int i = 0; i < 4; ++i) wA[i] = pack8(fA[i][0], fA[i][1]);
        #pragma unroll
        for (int i = 0; i < 2; ++i) wB[i] = pack8(fB[i][0], fB[i][1]);

        if (kt < 7) { loadA((kt + 1) * 64); loadB((kt + 1) * 64); }

        __syncthreads();
        #pragma unroll
        for (int i = 0; i < 4; ++i)
            *(bf16x8*)(As + (srow + 32 * i) * 128 + sswz) = wA[i];
        #pragma unroll
        for (int i = 0; i < 2; ++i)
            *(bf16x8*)(Bs + (srow + 32 * i) * 128 + sswz) = wB[i];
        __syncthreads();

        #pragma unroll
        for (int kc = 0; kc < 2; ++kc) {
            bf16x8 af[4], bfr[2];
            #pragma unroll
            for (int fm = 0; fm < 4; ++fm) {
                int row = wr * 64 + fm * 16 + lr;
                af[fm] = *(const bf16x8*)(As + row * 128 + (((kc * 4 + lg) ^ (row & 7)) * 16));
            }
            #pragma unroll
            for (int fn = 0; fn < 2; ++fn) {
                int row = wc * 32 + fn * 16 + lr;
                bfr[fn] = *(const bf16x8*)(Bs + row * 128 + (((kc * 4 + lg) ^ (row & 7)) * 16));
            }
            #pragma unroll
            for (int fm = 0; fm < 4; ++fm)
                #pragma unroll
                for (int fn = 0; fn < 2; ++fn)
                    acc[fm][fn] = __builtin_amdgcn_mfma_f32_16x16x32_bf16(af[fm], bfr[fn], acc[fm][fn], 0, 0, 0);
        }
    }

    const float scale = (mat == 0) ? CQ : 1.0f;
    #pragma unroll
    for (int fm = 0; fm < 4; ++fm) {
        #pragma unroll
        for (int fn = 0; fn < 2; ++fn) {
            int n = n0 + wc * 32 + fn * 16 + lr;
            float bn = bias[n];
            int mbase = m0 + wr * 64 + fm * 16 + lg * 4;
            int h = n >> 6, d = n & 63;
            if (mat < 2) {
                unsigned short* Y = (mat == 0) ? Yq : Yk;
                #pragma unroll
                for (int r = 0; r < 4; ++r) {
                    int m = mbase + r, b = m >> 12, s = m & (S - 1);
                    Y[(((size_t)(b * HH + h)) * S + s) * DK + d] =
                        (unsigned short)f2bs((acc[fm][fn][r] + bn) * scale);
                }
            } else {
                int b = mbase >> 12, s = mbase & (S - 1);
                ushort4 u;
                u.x = (unsigned short)f2bs(acc[fm][fn][0] + bn);
                u.y = (unsigned short)f2bs(acc[fm][fn][1] + bn);
                u.z = (unsigned short)f2bs(acc[fm][fn][2] + bn);
                u.w = (unsigned short)f2bs(acc[fm][fn][3] + bn);
                *(ushort4*)(Yv + ((size_t)((b * HH + h) * DK + d)) * S + s) = u;
            }
        }
    }
}

// ---------------- Output projection (unchanged) ----------------
__global__ __launch_bounds__(256, 2)
void out_gemm(const short* __restrict__ Xb, const float* __restrict__ W,
              const float* __restrict__ bias, float* __restrict__ Y)
{
    __shared__ char As[128 * 128];
    __shared__ char Bs[64 * 128];
    const int t = threadIdx.x, l = t & 63, w = t >> 6;
    const int wr = w >> 1, wc = w & 1;
    const int m0 = blockIdx.y * 128, n0 = blockIdx.x * 64;
    const int lr = l & 15, lg = l >> 4;
    const int srow = t >> 3, schk = t & 7;
    const int sswz = (schk ^ (srow & 7)) * 16;

    float4 fB[2][2]; bf16x8 rA[4];
    auto loadA = [&](int k0) {
        #pragma unroll
        for (int i = 0; i < 4; ++i)
            rA[i] = *(const bf16x8*)(Xb + (size_t)(m0 + srow + 32 * i) * DM + k0 + schk * 8);
    };
    auto loadB = [&](int k0) {
        #pragma unroll
        for (int i = 0; i < 2; ++i) {
            const float* p = W + (size_t)(n0 + srow + 32 * i) * DM + k0 + schk * 8;
            fB[i][0] = *(const float4*)p;
            fB[i][1] = *(const float4*)(p + 4);
        }
    };

    loadA(0); loadB(0);

    f32x4 acc[4][2];
    #pragma unroll
    for (int fm = 0; fm < 4; ++fm)
        #pragma unroll
        for (int fn = 0; fn < 2; ++fn) acc[fm][fn] = f32x4{0.f, 0.f, 0.f, 0.f};

    #pragma unroll
    for (int kt = 0; kt < 8; ++kt) {
        bf16x8 wA[4], wB[2];
        #pragma unroll
        for (int i = 0; i < 4; ++i) wA[i] = rA[i];
        #pragma unroll
        for (int i = 0; i < 2; ++i) wB[i] = pack8(fB[i][0], fB[i][1]);

        if (kt < 7) { loadA((kt + 1) * 64); loadB((kt + 1) * 64); }

        __syncthreads();
        #pragma unroll
        for (int i = 0; i < 4; ++i)
            *(bf16x8*)(As + (srow + 32 * i) * 128 + sswz) = wA[i];
        #pragma unroll
        for (int i = 0; i < 2; ++i)
            *(bf16x8*)(Bs + (srow + 32 * i) * 128 + sswz) = wB[i];
        __syncthreads();

        #pragma unroll
        for (int kc = 0; kc < 2; ++kc) {
            bf16x8 af[4], bfr[2];
            #pragma unroll
            for (int fm = 0; fm < 4; ++fm) {
                int row = wr * 64 + fm * 16 + lr;
                af[fm] = *(const bf16x8*)(As + row * 128 + (((kc * 4 + lg) ^ (row & 7)) * 16));
            }
            #pragma unroll
            for (int fn = 0; fn < 2; ++fn) {
                int row = wc * 32 + fn * 16 + lr;
                bfr[fn] = *(const bf16x8*)(Bs + row * 128 + (((kc * 4 + lg) ^ (row & 7)) * 16));
            }
            #pragma unroll
            for (int fm = 0; fm < 4; ++fm)
                #pragma unroll
                for (int fn = 0; fn < 2; ++fn)
                    acc[fm][fn] = __builtin_amdgcn_mfma_f32_16x16x32_bf16(af[fm], bfr[fn], acc[fm][fn], 0, 0, 0);
        }
    }

    #pragma unroll
    for (int fm = 0; fm < 4; ++fm) {
        #pragma unroll
        for (int fn = 0; fn < 2; ++fn) {
            int n = n0 + wc * 32 + fn * 16 + lr;
            float bn = bias[n];
            int mbase = m0 + wr * 64 + fm * 16 + lg * 4;
            #pragma unroll
            for (int r = 0; r < 4; ++r)
                Y[(size_t)(mbase + r) * DM + n] = acc[fm][fn][r] + bn;
        }
    }
}

// ---------------- Flash attention: 32x32 MFMA, in-register P, hoisted ------
// qh: bf16 [bh][s][64] PRE-SCALED by CQ; kh: bf16 [bh][s][64]; vt: bf16 [bh][64][s].
// 2 waves/block, 32 q/wave. Swapped QK^T; mask staged as additive bias
// (0 / -3e38) and used as the MFMA C-init (exp2(-3e38+s)=0). KV loop unrolled
// x2 with compile-time buffer indices so all LDS addresses are loop-invariant.
__global__ __launch_bounds__(128, 2)
void flash_mfma(const __hip_bfloat16* __restrict__ qh,
                const __hip_bfloat16* __restrict__ kh,
                const __hip_bfloat16* __restrict__ vt,
                const int* __restrict__ mask,
                __hip_bfloat16* __restrict__ att)
{
    const int bh = blockIdx.y, b = bh >> 3, h = bh & 7;
    const int q0 = blockIdx.x * 64;
    const int t = threadIdx.x, w = t >> 6, l = t & 63;
    const int l31 = l & 31, hi = l >> 5;

    __shared__ char  KsB[2][8192];   // [key 64][dk 64] bf16, 16B-chunk XOR swz
    __shared__ char  VsB[2][8192];   // [d 64][key 64] bf16, same swz
    __shared__ float mskf[2][KVB];   // additive mask bias: 0 or -3e38

    const short* qg = (const short*)qh + ((size_t)bh * S + q0 + w * 32 + l31) * DK;
    bf16x8 qf[4];
    #pragma unroll
    for (int c = 0; c < 4; ++c)
        qf[c] = *(const bf16x8*)(qg + c * 16 + hi * 8);

    f32x16 oc[2];
    #pragma unroll
    for (int dt = 0; dt < 2; ++dt)
        #pragma unroll
        for (int r = 0; r < 16; ++r) oc[dt][r] = 0.f;
    float lsum = 0.f;

    const int sr = t >> 1, sc4 = (t & 1) * 4;

    // advancing global source pointers (fixed stride per tile)
    const short* ksrc = (const short*)kh + (size_t)bh * S * DK + (size_t)sr * DK + sc4 * 8;
    const short* vsrc = (const short*)vt + (size_t)bh * DK * S + (size_t)sr * S + sc4 * 8;
    const int*   msrc = mask + b * S + (t & (KVB - 1));

    bf16x8 rK[4], rV[4];
    float  mreg = 0.f;

    auto issue = [&]() {
        #pragma unroll
        for (int i = 0; i < 4; ++i) rK[i] = *(const bf16x8*)(ksrc + i * 8);
        #pragma unroll
        for (int i = 0; i < 4; ++i) rV[i] = *(const bf16x8*)(vsrc + i * 8);
        if (t < KVB) mreg = msrc[0] ? 0.f : -3e38f;
        ksrc += KVB * DK; vsrc += KVB; msrc += KVB;
    };
    auto stageTo = [&](char* kb, char* vb, float* mf) {
        #pragma unroll
        for (int i = 0; i < 4; ++i)
            *(bf16x8*)(kb + sr * 128 + (((sc4 + i) ^ (sr & 7)) * 16)) = rK[i];
        #pragma unroll
        for (int i = 0; i < 4; ++i)
            *(bf16x8*)(vb + sr * 128 + (((sc4 + i) ^ (sr & 7)) * 16)) = rV[i];
        if (t < KVB) mf[t] = mreg;
    };

    auto tile = [&](const char* kb, const char* vb, const float* mf) {
        // ---- QK^T (swapped, both 32-key halves, mask-bias C-init)
        f32x16 sc0, sc1;
        #pragma unroll
        for (int g = 0; g < 4; ++g) {
            f32x4 m0 = *(const f32x4*)(mf + g * 8 + hi * 4);
            f32x4 m1 = *(const f32x4*)(mf + 32 + g * 8 + hi * 4);
            #pragma unroll
            for (int o = 0; o < 4; ++o) { sc0[g * 4 + o] = m0[o]; sc1[g * 4 + o] = m1[o]; }
        }
        const int kr0 = l31, kr1 = 32 + l31;
        __builtin_amdgcn_s_setprio(1);
        #pragma unroll
        for (int c = 0; c < 4; ++c) {
            bf16x8 kf0 = *(const bf16x8*)(kb + kr0 * 128 + (((c * 2 + hi) ^ (kr0 & 7)) * 16));
            bf16x8 kf1 = *(const bf16x8*)(kb + kr1 * 128 + (((c * 2 + hi) ^ (kr1 & 7)) * 16));
            sc0 = __builtin_amdgcn_mfma_f32_32x32x16_bf16(kf0, qf[c], sc0, 0, 0, 0);
            sc1 = __builtin_amdgcn_mfma_f32_32x32x16_bf16(kf1, qf[c], sc1, 0, 0, 0);
        }
        __builtin_amdgcn_s_setprio(0);

        // ---- p = exp2(sc); per-lane l partials
        float p0[16], p1[16];
        #pragma unroll
        for (int r = 0; r < 16; ++r) { p0[r] = exp2f(sc0[r]); p1[r] = exp2f(sc1[r]); }
        float s0 = 0.f, s1 = 0.f;
        #pragma unroll
        for (int r = 0; r < 16; r += 4) {
            s0 += (p0[r] + p0[r + 1]) + (p0[r + 2] + p0[r + 3]);
            s1 += (p1[r] + p1[r + 1]) + (p1[r + 2] + p1[r + 3]);
        }
        lsum += s0 + s1;

        // ---- cvt_pk + permlane32_swap -> PV B-frags (kc = 0..3)
        bf16x8 pb[4];
        {
            unsigned A0 = cvtpk(p0[0],  p0[1]),  B0 = cvtpk(p0[2],  p0[3]);
            unsigned A1 = cvtpk(p0[4],  p0[5]),  B1 = cvtpk(p0[6],  p0[7]);
            unsigned A2 = cvtpk(p0[8],  p0[9]),  B2 = cvtpk(p0[10], p0[11]);
            unsigned A3 = cvtpk(p0[12], p0[13]), B3 = cvtpk(p0[14], p0[15]);
            asm("v_permlane32_swap_b32 %0, %1" : "+v"(A0), "+v"(A1));
            asm("v_permlane32_swap_b32 %0, %1" : "+v"(B0), "+v"(B1));
            asm("v_permlane32_swap_b32 %0, %1" : "+v"(A2), "+v"(A3));
            asm("v_permlane32_swap_b32 %0, %1" : "+v"(B2), "+v"(B3));
            pb[0] = mk_pb(A0, B0, A1, B1);
            pb[1] = mk_pb(A2, B2, A3, B3);
        }
        {
            unsigned A0 = cvtpk(p1[0],  p1[1]),  B0 = cvtpk(p1[2],  p1[3]);
            unsigned A1 = cvtpk(p1[4],  p1[5]),  B1 = cvtpk(p1[6],  p1[7]);
            unsigned A2 = cvtpk(p1[8],  p1[9]),  B2 = cvtpk(p1[10], p1[11]);
            unsigned A3 = cvtpk(p1[12], p1[13]), B3 = cvtpk(p1[14], p1[15]);
            asm("v_permlane32_swap_b32 %0, %1" : "+v"(A0), "+v"(A1));
            asm("v_permlane32_swap_b32 %0, %1" : "+v"(B0), "+v"(B1));
            asm("v_permlane32_swap_b32 %0, %1" : "+v"(A2), "+v"(A3));
            asm("v_permlane32_swap_b32 %0, %1" : "+v"(B2), "+v"(B3));
            pb[2] = mk_pb(A0, B0, A1, B1);
            pb[3] = mk_pb(A2, B2, A3, B3);
        }

        // ---- PV (swapped): oc[dt] += mfma(V', P)
        const int vr0 = l31, vr1 = 32 + l31;
        __builtin_amdgcn_s_setprio(1);
        #pragma unroll
        for (int kc = 0; kc < 4; ++kc) {
            bf16x8 vf0 = *(const bf16x8*)(vb + vr0 * 128 + (((kc * 2 + hi) ^ (vr0 & 7)) * 16));
            bf16x8 vf1 = *(const bf16x8*)(vb + vr1 * 128 + (((kc * 2 + hi) ^ (vr1 & 7)) * 16));
            oc[0] = __builtin_amdgcn_mfma_f32_32x32x16_bf16(vf0, pb[kc], oc[0], 0, 0, 0);
            oc[1] = __builtin_amdgcn_mfma_f32_32x32x16_bf16(vf1, pb[kc], oc[1], 0, 0, 0);
        }
        __builtin_amdgcn_s_setprio(0);
    };

    const int NT = S / KVB;   // 64 (even)
    issue(); stageTo(KsB[0], VsB[0], mskf[0]); issue();

    for (int it2 = 0; it2 < NT / 2; ++it2) {
        const int it = it2 * 2;
        __syncthreads();
        stageTo(KsB[1], VsB[1], mskf[1]);          // tile it+1 (always valid: it <= NT-2)
        if (it < NT - 2) issue();                  // tile it+2
        tile(KsB[0], VsB[0], mskf[0]);
        __syncthreads();
        if (it + 1 < NT - 1) stageTo(KsB[0], VsB[0], mskf[0]);  // tile it+2
        if (it + 1 < NT - 2) issue();              // tile it+3
        tile(KsB[1], VsB[1], mskf[1]);
    }

    // ---- epilogue
    lsum += __shfl_xor(lsum, 32);
    const float linv = 1.0f / lsum;
    const int q = q0 + w * 32 + l31;
    unsigned short* ap = (unsigned short*)att + ((size_t)(b * S + q)) * DM + h * DK;
    #pragma unroll
    for (int dt = 0; dt < 2; ++dt)
        #pragma unroll
        for (int g = 0; g < 4; ++g) {
            unsigned lo  = cvtpk(oc[dt][g * 4 + 0] * linv, oc[dt][g * 4 + 1] * linv);
            unsigned hi2 = cvtpk(oc[dt][g * 4 + 2] * linv, oc[dt][g * 4 + 3] * linv);
            uint2 u; u.x = lo; u.y = hi2;
            *(uint2*)(ap + dt * 32 + g * 8 + hi * 4) = u;
        }
}

extern "C" void kernel_launch(void* const* d_in, const int* in_sizes, int n_in,
                              void* d_out, int out_size, void* d_ws, size_t ws_size,
                              hipStream_t stream) {
    const float* q    = (const float*)d_in[0];
    const float* k    = (const float*)d_in[1];
    const float* v    = (const float*)d_in[2];
    const int*   mask = (const int*)  d_in[3];
    const float* wq   = (const float*)d_in[4];
    const float* bq   = (const float*)d_in[5];
    const float* wk   = (const float*)d_in[6];
    const float* bk   = (const float*)d_in[7];
    const float* wv   = (const float*)d_in[8];
    const float* bv   = (const float*)d_in[9];
    const float* wo   = (const float*)d_in[10];
    const float* bo   = (const float*)d_in[11];
    float* out = (float*)d_out;

    char* wsb = (char*)d_ws;
    __hip_bfloat16* qh  = (__hip_bfloat16*)(wsb);
    __hip_bfloat16* kh  = (__hip_bfloat16*)(wsb + (size_t)8  * 1024 * 1024);
    __hip_bfloat16* vt  = (__hip_bfloat16*)(wsb + (size_t)16 * 1024 * 1024);
    __hip_bfloat16* att = (__hip_bfloat16*)(wsb + (size_t)24 * 1024 * 1024);

    dim3 blk(256);
    dim3 gq(24, MT / 128);                 // fused QKV: 1536 blocks
    qkv_gemm<<<gq, blk, 0, stream>>>(q, k, v, wq, wk, wv, bq, bk, bv,
                                     (unsigned short*)qh, (unsigned short*)kh,
                                     (unsigned short*)vt);

    dim3 g2(S / 64, 16);                   // 1024 blocks, 128 threads, 32 q/wave
    flash_mfma<<<g2, dim3(128), 0, stream>>>(qh, kh, vt, mask, att);

    dim3 gg(DM / 64, MT / 128);            // (8, 64)
    out_gemm<<<gg, blk, 0, stream>>>((const short*)att, wo, bo, out);
}

// Round 9
// 204.781 us; speedup vs baseline: 1.0662x; 1.0003x over previous
//
#include <hip/hip_runtime.h>
#include <hip/hip_bf16.h>

#define S 4096
#define DM 512
#define HH 8
#define DK 64
#define MT 8192     // B*S
#define KVB 64

typedef __attribute__((ext_vector_type(8)))  short bf16x8;
typedef __attribute__((ext_vector_type(4)))  float f32x4;
typedef __attribute__((ext_vector_type(16))) float f32x16;
typedef __attribute__((ext_vector_type(4)))  unsigned int u32x4;

#define CQ 0.18033688011112042f   // 0.125 * log2(e), folded into Q projection

__device__ __forceinline__ short f2bs(float x) {
    __hip_bfloat16 h = __float2bfloat16(x);
    return *reinterpret_cast<short*>(&h);
}

__device__ __forceinline__ bf16x8 pack8(const float4& a, const float4& b) {
    bf16x8 r;
    r[0] = f2bs(a.x); r[1] = f2bs(a.y); r[2] = f2bs(a.z); r[3] = f2bs(a.w);
    r[4] = f2bs(b.x); r[5] = f2bs(b.y); r[6] = f2bs(b.z); r[7] = f2bs(b.w);
    return r;
}

__device__ __forceinline__ unsigned cvtpk(float lo, float hi) {
    unsigned r;
    asm("v_cvt_pk_bf16_f32 %0, %1, %2" : "=v"(r) : "v"(lo), "v"(hi));
    return r;
}

__device__ __forceinline__ bf16x8 mk_pb(unsigned a, unsigned b, unsigned c, unsigned d) {
    u32x4 t; t[0] = a; t[1] = b; t[2] = c; t[3] = d;
    return __builtin_bit_cast(bf16x8, t);
}

// ---------------- Fused QKV projection (unchanged) ----------------
__global__ __launch_bounds__(256, 4)
void qkv_gemm(const float* __restrict__ Xq, const float* __restrict__ Xk,
              const float* __restrict__ Xv,
              const float* __restrict__ Wq, const float* __restrict__ Wk,
              const float* __restrict__ Wv,
              const float* __restrict__ Bq, const float* __restrict__ Bk,
              const float* __restrict__ Bv,
              unsigned short* __restrict__ Yq, unsigned short* __restrict__ Yk,
              unsigned short* __restrict__ Yv)
{
    __shared__ char As[128 * 128];
    __shared__ char Bs[64 * 128];
    const int mat = blockIdx.x >> 3;
    const int n0  = (blockIdx.x & 7) * 64;
    const int m0  = blockIdx.y * 128;
    const float* X    = mat == 0 ? Xq : (mat == 1 ? Xk : Xv);
    const float* W    = mat == 0 ? Wq : (mat == 1 ? Wk : Wv);
    const float* bias = mat == 0 ? Bq : (mat == 1 ? Bk : Bv);

    const int t = threadIdx.x, l = t & 63, w = t >> 6;
    const int wr = w >> 1, wc = w & 1;
    const int lr = l & 15, lg = l >> 4;
    const int srow = t >> 3, schk = t & 7;
    const int sswz = (schk ^ (srow & 7)) * 16;

    float4 fA[4][2]; float4 fB[2][2];
    auto loadA = [&](int k0) {
        #pragma unroll
        for (int i = 0; i < 4; ++i) {
            const float* p = X + (size_t)(m0 + srow + 32 * i) * DM + k0 + schk * 8;
            fA[i][0] = *(const float4*)p;
            fA[i][1] = *(const float4*)(p + 4);
        }
    };
    auto loadB = [&](int k0) {
        #pragma unroll
        for (int i = 0; i < 2; ++i) {
            const float* p = W + (size_t)(n0 + srow + 32 * i) * DM + k0 + schk * 8;
            fB[i][0] = *(const float4*)p;
            fB[i][1] = *(const float4*)(p + 4);
        }
    };

    loadA(0); loadB(0);

    f32x4 acc[4][2];
    #pragma unroll
    for (int fm = 0; fm < 4; ++fm)
        #pragma unroll
        for (int fn = 0; fn < 2; ++fn) acc[fm][fn] = f32x4{0.f, 0.f, 0.f, 0.f};

    #pragma unroll
    for (int kt = 0; kt < 8; ++kt) {
        bf16x8 wA[4], wB[2];
        #pragma unroll
        for (int i = 0; i < 4; ++i) wA[i] = pack8(fA[i][0], fA[i][1]);
        #pragma unroll
        for (int i = 0; i < 2; ++i) wB[i] = pack8(fB[i][0], fB[i][1]);

        if (kt < 7) { loadA((kt + 1) * 64); loadB((kt + 1) * 64); }

        __syncthreads();
        #pragma unroll
        for (int i = 0; i < 4; ++i)
            *(bf16x8*)(As + (srow + 32 * i) * 128 + sswz) = wA[i];
        #pragma unroll
        for (int i = 0; i < 2; ++i)
            *(bf16x8*)(Bs + (srow + 32 * i) * 128 + sswz) = wB[i];
        __syncthreads();

        #pragma unroll
        for (int kc = 0; kc < 2; ++kc) {
            bf16x8 af[4], bfr[2];
            #pragma unroll
            for (int fm = 0; fm < 4; ++fm) {
                int row = wr * 64 + fm * 16 + lr;
                af[fm] = *(const bf16x8*)(As + row * 128 + (((kc * 4 + lg) ^ (row & 7)) * 16));
            }
            #pragma unroll
            for (int fn = 0; fn < 2; ++fn) {
                int row = wc * 32 + fn * 16 + lr;
                bfr[fn] = *(const bf16x8*)(Bs + row * 128 + (((kc * 4 + lg) ^ (row & 7)) * 16));
            }
            #pragma unroll
            for (int fm = 0; fm < 4; ++fm)
                #pragma unroll
                for (int fn = 0; fn < 2; ++fn)
                    acc[fm][fn] = __builtin_amdgcn_mfma_f32_16x16x32_bf16(af[fm], bfr[fn], acc[fm][fn], 0, 0, 0);
        }
    }

    const float scale = (mat == 0) ? CQ : 1.0f;
    #pragma unroll
    for (int fm = 0; fm < 4; ++fm) {
        #pragma unroll
        for (int fn = 0; fn < 2; ++fn) {
            int n = n0 + wc * 32 + fn * 16 + lr;
            float bn = bias[n];
            int mbase = m0 + wr * 64 + fm * 16 + lg * 4;
            int h = n >> 6, d = n & 63;
            if (mat < 2) {
                unsigned short* Y = (mat == 0) ? Yq : Yk;
                #pragma unroll
                for (int r = 0; r < 4; ++r) {
                    int m = mbase + r, b = m >> 12, s = m & (S - 1);
                    Y[(((size_t)(b * HH + h)) * S + s) * DK + d] =
                        (unsigned short)f2bs((acc[fm][fn][r] + bn) * scale);
                }
            } else {
                int b = mbase >> 12, s = mbase & (S - 1);
                ushort4 u;
                u.x = (unsigned short)f2bs(acc[fm][fn][0] + bn);
                u.y = (unsigned short)f2bs(acc[fm][fn][1] + bn);
                u.z = (unsigned short)f2bs(acc[fm][fn][2] + bn);
                u.w = (unsigned short)f2bs(acc[fm][fn][3] + bn);
                *(ushort4*)(Yv + ((size_t)((b * HH + h) * DK + d)) * S + s) = u;
            }
        }
    }
}

// ---------------- Output projection (unchanged) ----------------
__global__ __launch_bounds__(256, 2)
void out_gemm(const short* __restrict__ Xb, const float* __restrict__ W,
              const float* __restrict__ bias, float* __restrict__ Y)
{
    __shared__ char As[128 * 128];
    __shared__ char Bs[64 * 128];
    const int t = threadIdx.x, l = t & 63, w = t >> 6;
    const int wr = w >> 1, wc = w & 1;
    const int m0 = blockIdx.y * 128, n0 = blockIdx.x * 64;
    const int lr = l & 15, lg = l >> 4;
    const int srow = t >> 3, schk = t & 7;
    const int sswz = (schk ^ (srow & 7)) * 16;

    float4 fB[2][2]; bf16x8 rA[4];
    auto loadA = [&](int k0) {
        #pragma unroll
        for (int i = 0; i < 4; ++i)
            rA[i] = *(const bf16x8*)(Xb + (size_t)(m0 + srow + 32 * i) * DM + k0 + schk * 8);
    };
    auto loadB = [&](int k0) {
        #pragma unroll
        for (int i = 0; i < 2; ++i) {
            const float* p = W + (size_t)(n0 + srow + 32 * i) * DM + k0 + schk * 8;
            fB[i][0] = *(const float4*)p;
            fB[i][1] = *(const float4*)(p + 4);
        }
    };

    loadA(0); loadB(0);

    f32x4 acc[4][2];
    #pragma unroll
    for (int fm = 0; fm < 4; ++fm)
        #pragma unroll
        for (int fn = 0; fn < 2; ++fn) acc[fm][fn] = f32x4{0.f, 0.f, 0.f, 0.f};

    #pragma unroll
    for (int kt = 0; kt < 8; ++kt) {
        bf16x8 wA[4], wB[2];
        #pragma unroll
        for (int i = 0; i < 4; ++i) wA[i] = rA[i];
        #pragma unroll
        for (int i = 0; i < 2; ++i) wB[i] = pack8(fB[i][0], fB[i][1]);

        if (kt < 7) { loadA((kt + 1) * 64); loadB((kt + 1) * 64); }

        __syncthreads();
        #pragma unroll
        for (int i = 0; i < 4; ++i)
            *(bf16x8*)(As + (srow + 32 * i) * 128 + sswz) = wA[i];
        #pragma unroll
        for (int i = 0; i < 2; ++i)
            *(bf16x8*)(Bs + (srow + 32 * i) * 128 + sswz) = wB[i];
        __syncthreads();

        #pragma unroll
        for (int kc = 0; kc < 2; ++kc) {
            bf16x8 af[4], bfr[2];
            #pragma unroll
            for (int fm = 0; fm < 4; ++fm) {
                int row = wr * 64 + fm * 16 + lr;
                af[fm] = *(const bf16x8*)(As + row * 128 + (((kc * 4 + lg) ^ (row & 7)) * 16));
            }
            #pragma unroll
            for (int fn = 0; fn < 2; ++fn) {
                int row = wc * 32 + fn * 16 + lr;
                bfr[fn] = *(const bf16x8*)(Bs + row * 128 + (((kc * 4 + lg) ^ (row & 7)) * 16));
            }
            #pragma unroll
            for (int fm = 0; fm < 4; ++fm)
                #pragma unroll
                for (int fn = 0; fn < 2; ++fn)
                    acc[fm][fn] = __builtin_amdgcn_mfma_f32_16x16x32_bf16(af[fm], bfr[fn], acc[fm][fn], 0, 0, 0);
        }
    }

    #pragma unroll
    for (int fm = 0; fm < 4; ++fm) {
        #pragma unroll
        for (int fn = 0; fn < 2; ++fn) {
            int n = n0 + wc * 32 + fn * 16 + lr;
            float bn = bias[n];
            int mbase = m0 + wr * 64 + fm * 16 + lg * 4;
            #pragma unroll
            for (int r = 0; r < 4; ++r)
                Y[(size_t)(mbase + r) * DM + n] = acc[fm][fn][r] + bn;
        }
    }
}

// ---------------- Flash attention: key-split waves, shared A-reads ----------
// qh: bf16 [bh][s][64] PRE-SCALED by CQ; kh: bf16 [bh][s][64]; vt: bf16 [bh][64][s].
// Block = 128 threads / 2 waves covering 64 q. Wave w owns keys [w*32, w*32+32)
// of each KV tile and computes BOTH 32-q column blocks, so every K/V LDS read
// feeds 2 MFMAs. Partial O/lsum reduced across waves once at kernel end.
__global__ __launch_bounds__(128, 2)
void flash_mfma(const __hip_bfloat16* __restrict__ qh,
                const __hip_bfloat16* __restrict__ kh,
                const __hip_bfloat16* __restrict__ vt,
                const int* __restrict__ mask,
                __hip_bfloat16* __restrict__ att)
{
    const int bh = blockIdx.y, b = bh >> 3, h = bh & 7;
    const int q0 = blockIdx.x * 64;
    const int t = threadIdx.x, w = t >> 6, l = t & 63;
    const int l31 = l & 31, hi = l >> 5;

    __shared__ char sBuf[32768 + 2 * KVB * 4];
    char* Ks0 = sBuf;                 // [64][128B], 16B-chunk XOR swz
    char* Ks1 = sBuf + 8192;
    char* Vs0 = sBuf + 16384;         // V^T [d 64][key 64]
    char* Vs1 = sBuf + 24576;
    float* mskf = (float*)(sBuf + 32768);   // [2][KVB] additive bias 0 / -3e38

    // Q B-frags for both q-col-blocks (q = q0+l31 and q0+32+l31)
    const short* qg = (const short*)qh + ((size_t)bh * S + q0 + l31) * DK;
    bf16x8 qfA[4], qfB[4];
    #pragma unroll
    for (int c = 0; c < 4; ++c) {
        qfA[c] = *(const bf16x8*)(qg + c * 16 + hi * 8);
        qfB[c] = *(const bf16x8*)(qg + 32 * DK + c * 16 + hi * 8);
    }

    f32x16 ocA[2], ocB[2];
    #pragma unroll
    for (int dt = 0; dt < 2; ++dt)
        #pragma unroll
        for (int r = 0; r < 16; ++r) { ocA[dt][r] = 0.f; ocB[dt][r] = 0.f; }
    float lsA = 0.f, lsB = 0.f;

    const int sr = t >> 1, sc4 = (t & 1) * 4;
    const short* ksrc = (const short*)kh + (size_t)bh * S * DK + (size_t)sr * DK + sc4 * 8;
    const short* vsrc = (const short*)vt + (size_t)bh * DK * S + (size_t)sr * S + sc4 * 8;
    const int*   msrc = mask + b * S + (t & (KVB - 1));

    bf16x8 rK[4], rV[4];
    float  mreg = 0.f;

    auto issue = [&]() {
        #pragma unroll
        for (int i = 0; i < 4; ++i) rK[i] = *(const bf16x8*)(ksrc + i * 8);
        #pragma unroll
        for (int i = 0; i < 4; ++i) rV[i] = *(const bf16x8*)(vsrc + i * 8);
        if (t < KVB) mreg = msrc[0] ? 0.f : -3e38f;
        ksrc += KVB * DK; vsrc += KVB; msrc += KVB;
    };
    auto stageTo = [&](char* kb, char* vb, float* mf) {
        #pragma unroll
        for (int i = 0; i < 4; ++i)
            *(bf16x8*)(kb + sr * 128 + (((sc4 + i) ^ (sr & 7)) * 16)) = rK[i];
        #pragma unroll
        for (int i = 0; i < 4; ++i)
            *(bf16x8*)(vb + sr * 128 + (((sc4 + i) ^ (sr & 7)) * 16)) = rV[i];
        if (t < KVB) mf[t] = mreg;
    };

    const int kbase = w * 32;            // wave's key block within the tile
    const int kr    = kbase + l31;       // K LDS row for QK A-operand

    auto tile = [&](const char* kb, const char* vb, const float* mf) {
        // ---- mask-bias C-init (shared by both q-blocks)
        f32x4 m4[4];
        #pragma unroll
        for (int g = 0; g < 4; ++g)
            m4[g] = *(const f32x4*)(mf + kbase + g * 8 + hi * 4);
        f32x16 sA, sB;
        #pragma unroll
        for (int g = 0; g < 4; ++g)
            #pragma unroll
            for (int o = 0; o < 4; ++o) { sA[g * 4 + o] = m4[g][o]; sB[g * 4 + o] = m4[g][o]; }

        // ---- QK^T (swapped): each kf read feeds both q-blocks
        __builtin_amdgcn_s_setprio(1);
        #pragma unroll
        for (int c = 0; c < 4; ++c) {
            bf16x8 kf = *(const bf16x8*)(kb + kr * 128 + (((c * 2 + hi) ^ (kr & 7)) * 16));
            sA = __builtin_amdgcn_mfma_f32_32x32x16_bf16(kf, qfA[c], sA, 0, 0, 0);
            sB = __builtin_amdgcn_mfma_f32_32x32x16_bf16(kf, qfB[c], sB, 0, 0, 0);
        }
        __builtin_amdgcn_s_setprio(0);

        // ---- p = exp2(s); per-lane l partials
        float pA[16], pB[16];
        #pragma unroll
        for (int r = 0; r < 16; ++r) { pA[r] = exp2f(sA[r]); pB[r] = exp2f(sB[r]); }
        float a0 = 0.f, b0 = 0.f;
        #pragma unroll
        for (int r = 0; r < 16; r += 4) {
            a0 += (pA[r] + pA[r + 1]) + (pA[r + 2] + pA[r + 3]);
            b0 += (pB[r] + pB[r + 1]) + (pB[r + 2] + pB[r + 3]);
        }
        lsA += a0; lsB += b0;

        // ---- cvt_pk + permlane32_swap -> PV B-frags
        bf16x8 pbA[2], pbB[2];
        {
            unsigned A0 = cvtpk(pA[0],  pA[1]),  B0 = cvtpk(pA[2],  pA[3]);
            unsigned A1 = cvtpk(pA[4],  pA[5]),  B1 = cvtpk(pA[6],  pA[7]);
            unsigned A2 = cvtpk(pA[8],  pA[9]),  B2 = cvtpk(pA[10], pA[11]);
            unsigned A3 = cvtpk(pA[12], pA[13]), B3 = cvtpk(pA[14], pA[15]);
            asm("v_permlane32_swap_b32 %0, %1" : "+v"(A0), "+v"(A1));
            asm("v_permlane32_swap_b32 %0, %1" : "+v"(B0), "+v"(B1));
            asm("v_permlane32_swap_b32 %0, %1" : "+v"(A2), "+v"(A3));
            asm("v_permlane32_swap_b32 %0, %1" : "+v"(B2), "+v"(B3));
            pbA[0] = mk_pb(A0, B0, A1, B1);
            pbA[1] = mk_pb(A2, B2, A3, B3);
        }
        {
            unsigned A0 = cvtpk(pB[0],  pB[1]),  B0 = cvtpk(pB[2],  pB[3]);
            unsigned A1 = cvtpk(pB[4],  pB[5]),  B1 = cvtpk(pB[6],  pB[7]);
            unsigned A2 = cvtpk(pB[8],  pB[9]),  B2 = cvtpk(pB[10], pB[11]);
            unsigned A3 = cvtpk(pB[12], pB[13]), B3 = cvtpk(pB[14], pB[15]);
            asm("v_permlane32_swap_b32 %0, %1" : "+v"(A0), "+v"(A1));
            asm("v_permlane32_swap_b32 %0, %1" : "+v"(B0), "+v"(B1));
            asm("v_permlane32_swap_b32 %0, %1" : "+v"(A2), "+v"(A3));
            asm("v_permlane32_swap_b32 %0, %1" : "+v"(B2), "+v"(B3));
            pbB[0] = mk_pb(A0, B0, A1, B1);
            pbB[1] = mk_pb(A2, B2, A3, B3);
        }

        // ---- PV: each vf read feeds both q-blocks
        __builtin_amdgcn_s_setprio(1);
        #pragma unroll
        for (int kcl = 0; kcl < 2; ++kcl) {
            #pragma unroll
            for (int dt = 0; dt < 2; ++dt) {
                const int vrow = dt * 32 + l31;
                bf16x8 vf = *(const bf16x8*)(vb + vrow * 128 +
                                (((w * 4 + kcl * 2 + hi) ^ (vrow & 7)) * 16));
                ocA[dt] = __builtin_amdgcn_mfma_f32_32x32x16_bf16(vf, pbA[kcl], ocA[dt], 0, 0, 0);
                ocB[dt] = __builtin_amdgcn_mfma_f32_32x32x16_bf16(vf, pbB[kcl], ocB[dt], 0, 0, 0);
            }
        }
        __builtin_amdgcn_s_setprio(0);
    };

    const int NT = S / KVB;   // 64 (even)
    issue(); stageTo(Ks0, Vs0, mskf); issue();

    for (int it2 = 0; it2 < NT / 2; ++it2) {
        const int it = it2 * 2;
        __syncthreads();
        stageTo(Ks1, Vs1, mskf + KVB);
        if (it < NT - 2) issue();
        tile(Ks0, Vs0, mskf);
        __syncthreads();
        if (it + 1 < NT - 1) stageTo(Ks0, Vs0, mskf);
        if (it + 1 < NT - 2) issue();
        tile(Ks1, Vs1, mskf + KVB);
    }

    // ---- cross-wave reduction (wave1 -> LDS -> wave0), then normalize+write
    __syncthreads();
    float* scr = (float*)sBuf;           // 8192 f32 available, need 64*68
    if (w == 1) {
        float* p = scr + l * 68;
        #pragma unroll
        for (int r = 0; r < 16; ++r) p[r]      = ocA[0][r];
        #pragma unroll
        for (int r = 0; r < 16; ++r) p[16 + r] = ocA[1][r];
        #pragma unroll
        for (int r = 0; r < 16; ++r) p[32 + r] = ocB[0][r];
        #pragma unroll
        for (int r = 0; r < 16; ++r) p[48 + r] = ocB[1][r];
        p[64] = lsA; p[65] = lsB;
    }
    __syncthreads();
    if (w == 0) {
        const float* p = scr + l * 68;
        #pragma unroll
        for (int r = 0; r < 16; ++r) ocA[0][r] += p[r];
        #pragma unroll
        for (int r = 0; r < 16; ++r) ocA[1][r] += p[16 + r];
        #pragma unroll
        for (int r = 0; r < 16; ++r) ocB[0][r] += p[32 + r];
        #pragma unroll
        for (int r = 0; r < 16; ++r) ocB[1][r] += p[48 + r];
        lsA += p[64]; lsB += p[65];
        lsA += __shfl_xor(lsA, 32);
        lsB += __shfl_xor(lsB, 32);
        const float liA = 1.0f / lsA, liB = 1.0f / lsB;

        unsigned short* apA = (unsigned short*)att +
            ((size_t)(b * S + q0 + l31)) * DM + h * DK;
        unsigned short* apB = (unsigned short*)att +
            ((size_t)(b * S + q0 + 32 + l31)) * DM + h * DK;
        #pragma unroll
        for (int dt = 0; dt < 2; ++dt)
            #pragma unroll
            for (int g = 0; g < 4; ++g) {
                uint2 uA, uB;
                uA.x = cvtpk(ocA[dt][g * 4 + 0] * liA, ocA[dt][g * 4 + 1] * liA);
                uA.y = cvtpk(ocA[dt][g * 4 + 2] * liA, ocA[dt][g * 4 + 3] * liA);
                uB.x = cvtpk(ocB[dt][g * 4 + 0] * liB, ocB[dt][g * 4 + 1] * liB);
                uB.y = cvtpk(ocB[dt][g * 4 + 2] * liB, ocB[dt][g * 4 + 3] * liB);
                *(uint2*)(apA + dt * 32 + g * 8 + hi * 4) = uA;
                *(uint2*)(apB + dt * 32 + g * 8 + hi * 4) = uB;
            }
    }
}

extern "C" void kernel_launch(void* const* d_in, const int* in_sizes, int n_in,
                              void* d_out, int out_size, void* d_ws, size_t ws_size,
                              hipStream_t stream) {
    const float* q    = (const float*)d_in[0];
    const float* k    = (const float*)d_in[1];
    const float* v    = (const float*)d_in[2];
    const int*   mask = (const int*)  d_in[3];
    const float* wq   = (const float*)d_in[4];
    const float* bq   = (const float*)d_in[5];
    const float* wk   = (const float*)d_in[6];
    const float* bk   = (const float*)d_in[7];
    const float* wv   = (const float*)d_in[8];
    const float* bv   = (const float*)d_in[9];
    const float* wo   = (const float*)d_in[10];
    const float* bo   = (const float*)d_in[11];
    float* out = (float*)d_out;

    char* wsb = (char*)d_ws;
    __hip_bfloat16* qh  = (__hip_bfloat16*)(wsb);
    __hip_bfloat16* kh  = (__hip_bfloat16*)(wsb + (size_t)8  * 1024 * 1024);
    __hip_bfloat16* vt  = (__hip_bfloat16*)(wsb + (size_t)16 * 1024 * 1024);
    __hip_bfloat16* att = (__hip_bfloat16*)(wsb + (size_t)24 * 1024 * 1024);

    dim3 blk(256);
    dim3 gq(24, MT / 128);                 // fused QKV: 1536 blocks
    qkv_gemm<<<gq, blk, 0, stream>>>(q, k, v, wq, wk, wv, bq, bk, bv,
                                     (unsigned short*)qh, (unsigned short*)kh,
                                     (unsigned short*)vt);

    dim3 g2(S / 64, 16);                   // 1024 blocks, 128 threads
    flash_mfma<<<g2, dim3(128), 0, stream>>>(qh, kh, vt, mask, att);

    dim3 gg(DM / 64, MT / 128);            // (8, 64)
    out_gemm<<<gg, blk, 0, stream>>>((const short*)att, wo, bo, out);
}

// Round 10
// 195.563 us; speedup vs baseline: 1.1165x; 1.0471x over previous
//
#include <hip/hip_runtime.h>
#include <hip/hip_bf16.h>

#define S 4096
#define DM 512
#define HH 8
#define DK 64
#define MT 8192     // B*S
#define KVB 64

typedef __attribute__((ext_vector_type(8)))  short bf16x8;
typedef __attribute__((ext_vector_type(4)))  float f32x4;
typedef __attribute__((ext_vector_type(16))) float f32x16;
typedef __attribute__((ext_vector_type(4)))  unsigned int u32x4;

#define CQ 0.18033688011112042f   // 0.125 * log2(e), folded into Q projection

__device__ __forceinline__ short f2bs(float x) {
    __hip_bfloat16 h = __float2bfloat16(x);
    return *reinterpret_cast<short*>(&h);
}

__device__ __forceinline__ bf16x8 pack8(const float4& a, const float4& b) {
    bf16x8 r;
    r[0] = f2bs(a.x); r[1] = f2bs(a.y); r[2] = f2bs(a.z); r[3] = f2bs(a.w);
    r[4] = f2bs(b.x); r[5] = f2bs(b.y); r[6] = f2bs(b.z); r[7] = f2bs(b.w);
    return r;
}

__device__ __forceinline__ unsigned cvtpk(float lo, float hi) {
    unsigned r;
    asm("v_cvt_pk_bf16_f32 %0, %1, %2" : "=v"(r) : "v"(lo), "v"(hi));
    return r;
}

__device__ __forceinline__ bf16x8 mk_pb(unsigned a, unsigned b, unsigned c, unsigned d) {
    u32x4 t; t[0] = a; t[1] = b; t[2] = c; t[3] = d;
    return __builtin_bit_cast(bf16x8, t);
}

// ---------------- Fused QKV projection (unchanged) ----------------
__global__ __launch_bounds__(256, 4)
void qkv_gemm(const float* __restrict__ Xq, const float* __restrict__ Xk,
              const float* __restrict__ Xv,
              const float* __restrict__ Wq, const float* __restrict__ Wk,
              const float* __restrict__ Wv,
              const float* __restrict__ Bq, const float* __restrict__ Bk,
              const float* __restrict__ Bv,
              unsigned short* __restrict__ Yq, unsigned short* __restrict__ Yk,
              unsigned short* __restrict__ Yv)
{
    __shared__ char As[128 * 128];
    __shared__ char Bs[64 * 128];
    const int mat = blockIdx.x >> 3;
    const int n0  = (blockIdx.x & 7) * 64;
    const int m0  = blockIdx.y * 128;
    const float* X    = mat == 0 ? Xq : (mat == 1 ? Xk : Xv);
    const float* W    = mat == 0 ? Wq : (mat == 1 ? Wk : Wv);
    const float* bias = mat == 0 ? Bq : (mat == 1 ? Bk : Bv);

    const int t = threadIdx.x, l = t & 63, w = t >> 6;
    const int wr = w >> 1, wc = w & 1;
    const int lr = l & 15, lg = l >> 4;
    const int srow = t >> 3, schk = t & 7;
    const int sswz = (schk ^ (srow & 7)) * 16;

    float4 fA[4][2]; float4 fB[2][2];
    auto loadA = [&](int k0) {
        #pragma unroll
        for (int i = 0; i < 4; ++i) {
            const float* p = X + (size_t)(m0 + srow + 32 * i) * DM + k0 + schk * 8;
            fA[i][0] = *(const float4*)p;
            fA[i][1] = *(const float4*)(p + 4);
        }
    };
    auto loadB = [&](int k0) {
        #pragma unroll
        for (int i = 0; i < 2; ++i) {
            const float* p = W + (size_t)(n0 + srow + 32 * i) * DM + k0 + schk * 8;
            fB[i][0] = *(const float4*)p;
            fB[i][1] = *(const float4*)(p + 4);
        }
    };

    loadA(0); loadB(0);

    f32x4 acc[4][2];
    #pragma unroll
    for (int fm = 0; fm < 4; ++fm)
        #pragma unroll
        for (int fn = 0; fn < 2; ++fn) acc[fm][fn] = f32x4{0.f, 0.f, 0.f, 0.f};

    #pragma unroll
    for (int kt = 0; kt < 8; ++kt) {
        bf16x8 wA[4], wB[2];
        #pragma unroll
        for (int i = 0; i < 4; ++i) wA[i] = pack8(fA[i][0], fA[i][1]);
        #pragma unroll
        for (int i = 0; i < 2; ++i) wB[i] = pack8(fB[i][0], fB[i][1]);

        if (kt < 7) { loadA((kt + 1) * 64); loadB((kt + 1) * 64); }

        __syncthreads();
        #pragma unroll
        for (int i = 0; i < 4; ++i)
            *(bf16x8*)(As + (srow + 32 * i) * 128 + sswz) = wA[i];
        #pragma unroll
        for (int i = 0; i < 2; ++i)
            *(bf16x8*)(Bs + (srow + 32 * i) * 128 + sswz) = wB[i];
        __syncthreads();

        #pragma unroll
        for (int kc = 0; kc < 2; ++kc) {
            bf16x8 af[4], bfr[2];
            #pragma unroll
            for (int fm = 0; fm < 4; ++fm) {
                int row = wr * 64 + fm * 16 + lr;
                af[fm] = *(const bf16x8*)(As + row * 128 + (((kc * 4 + lg) ^ (row & 7)) * 16));
            }
            #pragma unroll
            for (int fn = 0; fn < 2; ++fn) {
                int row = wc * 32 + fn * 16 + lr;
                bfr[fn] = *(const bf16x8*)(Bs + row * 128 + (((kc * 4 + lg) ^ (row & 7)) * 16));
            }
            #pragma unroll
            for (int fm = 0; fm < 4; ++fm)
                #pragma unroll
                for (int fn = 0; fn < 2; ++fn)
                    acc[fm][fn] = __builtin_amdgcn_mfma_f32_16x16x32_bf16(af[fm], bfr[fn], acc[fm][fn], 0, 0, 0);
        }
    }

    const float scale = (mat == 0) ? CQ : 1.0f;
    #pragma unroll
    for (int fm = 0; fm < 4; ++fm) {
        #pragma unroll
        for (int fn = 0; fn < 2; ++fn) {
            int n = n0 + wc * 32 + fn * 16 + lr;
            float bn = bias[n];
            int mbase = m0 + wr * 64 + fm * 16 + lg * 4;
            int h = n >> 6, d = n & 63;
            if (mat < 2) {
                unsigned short* Y = (mat == 0) ? Yq : Yk;
                #pragma unroll
                for (int r = 0; r < 4; ++r) {
                    int m = mbase + r, b = m >> 12, s = m & (S - 1);
                    Y[(((size_t)(b * HH + h)) * S + s) * DK + d] =
                        (unsigned short)f2bs((acc[fm][fn][r] + bn) * scale);
                }
            } else {
                int b = mbase >> 12, s = mbase & (S - 1);
                ushort4 u;
                u.x = (unsigned short)f2bs(acc[fm][fn][0] + bn);
                u.y = (unsigned short)f2bs(acc[fm][fn][1] + bn);
                u.z = (unsigned short)f2bs(acc[fm][fn][2] + bn);
                u.w = (unsigned short)f2bs(acc[fm][fn][3] + bn);
                *(ushort4*)(Yv + ((size_t)((b * HH + h) * DK + d)) * S + s) = u;
            }
        }
    }
}

// ---------------- Output projection (unchanged) ----------------
__global__ __launch_bounds__(256, 2)
void out_gemm(const short* __restrict__ Xb, const float* __restrict__ W,
              const float* __restrict__ bias, float* __restrict__ Y)
{
    __shared__ char As[128 * 128];
    __shared__ char Bs[64 * 128];
    const int t = threadIdx.x, l = t & 63, w = t >> 6;
    const int wr = w >> 1, wc = w & 1;
    const int m0 = blockIdx.y * 128, n0 = blockIdx.x * 64;
    const int lr = l & 15, lg = l >> 4;
    const int srow = t >> 3, schk = t & 7;
    const int sswz = (schk ^ (srow & 7)) * 16;

    float4 fB[2][2]; bf16x8 rA[4];
    auto loadA = [&](int k0) {
        #pragma unroll
        for (int i = 0; i < 4; ++i)
            rA[i] = *(const bf16x8*)(Xb + (size_t)(m0 + srow + 32 * i) * DM + k0 + schk * 8);
    };
    auto loadB = [&](int k0) {
        #pragma unroll
        for (int i = 0; i < 2; ++i) {
            const float* p = W + (size_t)(n0 + srow + 32 * i) * DM + k0 + schk * 8;
            fB[i][0] = *(const float4*)p;
            fB[i][1] = *(const float4*)(p + 4);
        }
    };

    loadA(0); loadB(0);

    f32x4 acc[4][2];
    #pragma unroll
    for (int fm = 0; fm < 4; ++fm)
        #pragma unroll
        for (int fn = 0; fn < 2; ++fn) acc[fm][fn] = f32x4{0.f, 0.f, 0.f, 0.f};

    #pragma unroll
    for (int kt = 0; kt < 8; ++kt) {
        bf16x8 wA[4], wB[2];
        #pragma unroll
        for (int i = 0; i < 4; ++i) wA[i] = rA[i];
        #pragma unroll
        for (int i = 0; i < 2; ++i) wB[i] = pack8(fB[i][0], fB[i][1]);

        if (kt < 7) { loadA((kt + 1) * 64); loadB((kt + 1) * 64); }

        __syncthreads();
        #pragma unroll
        for (int i = 0; i < 4; ++i)
            *(bf16x8*)(As + (srow + 32 * i) * 128 + sswz) = wA[i];
        #pragma unroll
        for (int i = 0; i < 2; ++i)
            *(bf16x8*)(Bs + (srow + 32 * i) * 128 + sswz) = wB[i];
        __syncthreads();

        #pragma unroll
        for (int kc = 0; kc < 2; ++kc) {
            bf16x8 af[4], bfr[2];
            #pragma unroll
            for (int fm = 0; fm < 4; ++fm) {
                int row = wr * 64 + fm * 16 + lr;
                af[fm] = *(const bf16x8*)(As + row * 128 + (((kc * 4 + lg) ^ (row & 7)) * 16));
            }
            #pragma unroll
            for (int fn = 0; fn < 2; ++fn) {
                int row = wc * 32 + fn * 16 + lr;
                bfr[fn] = *(const bf16x8*)(Bs + row * 128 + (((kc * 4 + lg) ^ (row & 7)) * 16));
            }
            #pragma unroll
            for (int fm = 0; fm < 4; ++fm)
                #pragma unroll
                for (int fn = 0; fn < 2; ++fn)
                    acc[fm][fn] = __builtin_amdgcn_mfma_f32_16x16x32_bf16(af[fm], bfr[fn], acc[fm][fn], 0, 0, 0);
        }
    }

    #pragma unroll
    for (int fm = 0; fm < 4; ++fm) {
        #pragma unroll
        for (int fn = 0; fn < 2; ++fn) {
            int n = n0 + wc * 32 + fn * 16 + lr;
            float bn = bias[n];
            int mbase = m0 + wr * 64 + fm * 16 + lg * 4;
            #pragma unroll
            for (int r = 0; r < 4; ++r)
                Y[(size_t)(mbase + r) * DM + n] = acc[fm][fn][r] + bn;
        }
    }
}

// ---------------- Flash attention: 4-wave blocks, 16 waves/CU ---------------
// qh: bf16 [bh][s][64] PRE-SCALED by CQ; kh: bf16 [bh][s][64]; vt: bf16 [bh][64][s].
// Block = 256 threads / 4 waves over 64 q. Wave (kw = w&1, qw = w>>1):
// keys [kw*32, kw*32+32), q-col qw*32 + l31. Per-wave state halved vs R9 so
// 4 waves/SIMD fit; occupancy doubles (latency-bound fix). Cross-wave (kw)
// reduction once at kernel end via LDS scratch.
__global__ __launch_bounds__(256, 4)
void flash_mfma(const __hip_bfloat16* __restrict__ qh,
                const __hip_bfloat16* __restrict__ kh,
                const __hip_bfloat16* __restrict__ vt,
                const int* __restrict__ mask,
                __hip_bfloat16* __restrict__ att)
{
    const int bh = blockIdx.y, b = bh >> 3, h = bh & 7;
    const int q0 = blockIdx.x * 64;
    const int t = threadIdx.x, w = t >> 6, l = t & 63;
    const int l31 = l & 31, hi = l >> 5;
    const int kw = w & 1, qw = w >> 1;

    __shared__ char sBuf[32768 + 2 * KVB * 4];
    char* Ks0 = sBuf;                 // K [64 key][128B], 16B-chunk XOR swz
    char* Ks1 = sBuf + 8192;
    char* Vs0 = sBuf + 16384;         // V^T [64 d][128B]
    char* Vs1 = sBuf + 24576;
    float* mskf = (float*)(sBuf + 32768);   // [2][KVB] additive bias 0/-3e38

    // Q B-frags: q-col = q0 + qw*32 + l31
    const short* qg = (const short*)qh + ((size_t)bh * S + q0 + qw * 32 + l31) * DK;
    bf16x8 qf[4];
    #pragma unroll
    for (int c = 0; c < 4; ++c)
        qf[c] = *(const bf16x8*)(qg + c * 16 + hi * 8);

    f32x16 oc[2];
    #pragma unroll
    for (int dt = 0; dt < 2; ++dt)
        #pragma unroll
        for (int r = 0; r < 16; ++r) oc[dt][r] = 0.f;
    float ls = 0.f;

    // staging: 64B/thread/buffer (rows of 128B, 4 threads/row -> coalesced)
    const int sr = t >> 2, c2 = (t & 3) * 2;
    const short* ksrc = (const short*)kh + (size_t)bh * S * DK + (size_t)sr * DK + c2 * 8;
    const short* vsrc = (const short*)vt + (size_t)bh * DK * S + (size_t)sr * S + c2 * 8;
    const int*   msrc = mask + b * S + (t & (KVB - 1));

    bf16x8 rK[2], rV[2];
    float  mreg = 0.f;

    auto issue = [&]() {
        rK[0] = *(const bf16x8*)(ksrc);
        rK[1] = *(const bf16x8*)(ksrc + 8);
        rV[0] = *(const bf16x8*)(vsrc);
        rV[1] = *(const bf16x8*)(vsrc + 8);
        if (t < KVB) mreg = msrc[0] ? 0.f : -3e38f;
        ksrc += KVB * DK; vsrc += KVB; msrc += KVB;
    };
    auto stageTo = [&](char* kb, char* vb, float* mf) {
        *(bf16x8*)(kb + sr * 128 + ((c2 ^ (sr & 7)) * 16))       = rK[0];
        *(bf16x8*)(kb + sr * 128 + (((c2 + 1) ^ (sr & 7)) * 16)) = rK[1];
        *(bf16x8*)(vb + sr * 128 + ((c2 ^ (sr & 7)) * 16))       = rV[0];
        *(bf16x8*)(vb + sr * 128 + (((c2 + 1) ^ (sr & 7)) * 16)) = rV[1];
        if (t < KVB) mf[t] = mreg;
    };

    const int kbase = kw * 32;
    const int kr    = kbase + l31;

    auto tile = [&](const char* kb, const char* vb, const float* mf) {
        // mask-bias C-init for this wave's 32 keys
        f32x16 sc;
        #pragma unroll
        for (int g = 0; g < 4; ++g) {
            f32x4 m4 = *(const f32x4*)(mf + kbase + g * 8 + hi * 4);
            #pragma unroll
            for (int o = 0; o < 4; ++o) sc[g * 4 + o] = m4[o];
        }
        // QK^T (swapped)
        __builtin_amdgcn_s_setprio(1);
        #pragma unroll
        for (int c = 0; c < 4; ++c) {
            bf16x8 kf = *(const bf16x8*)(kb + kr * 128 + (((c * 2 + hi) ^ (kr & 7)) * 16));
            sc = __builtin_amdgcn_mfma_f32_32x32x16_bf16(kf, qf[c], sc, 0, 0, 0);
        }
        __builtin_amdgcn_s_setprio(0);

        // p = exp2(s); per-lane l partial
        float p[16];
        #pragma unroll
        for (int r = 0; r < 16; ++r) p[r] = exp2f(sc[r]);
        float a0 = 0.f;
        #pragma unroll
        for (int r = 0; r < 16; r += 4)
            a0 += (p[r] + p[r + 1]) + (p[r + 2] + p[r + 3]);
        ls += a0;

        // cvt_pk + permlane32_swap -> PV B-frags
        unsigned A0 = cvtpk(p[0],  p[1]),  B0 = cvtpk(p[2],  p[3]);
        unsigned A1 = cvtpk(p[4],  p[5]),  B1 = cvtpk(p[6],  p[7]);
        unsigned A2 = cvtpk(p[8],  p[9]),  B2 = cvtpk(p[10], p[11]);
        unsigned A3 = cvtpk(p[12], p[13]), B3 = cvtpk(p[14], p[15]);
        asm("v_permlane32_swap_b32 %0, %1" : "+v"(A0), "+v"(A1));
        asm("v_permlane32_swap_b32 %0, %1" : "+v"(B0), "+v"(B1));
        asm("v_permlane32_swap_b32 %0, %1" : "+v"(A2), "+v"(A3));
        asm("v_permlane32_swap_b32 %0, %1" : "+v"(B2), "+v"(B3));
        bf16x8 pb0 = mk_pb(A0, B0, A1, B1);
        bf16x8 pb1 = mk_pb(A2, B2, A3, B3);

        // PV (swapped)
        __builtin_amdgcn_s_setprio(1);
        #pragma unroll
        for (int kcl = 0; kcl < 2; ++kcl) {
            const bf16x8 pb = kcl ? pb1 : pb0;
            #pragma unroll
            for (int dt = 0; dt < 2; ++dt) {
                const int vrow = dt * 32 + l31;
                bf16x8 vf = *(const bf16x8*)(vb + vrow * 128 +
                                (((kw * 4 + kcl * 2 + hi) ^ (vrow & 7)) * 16));
                oc[dt] = __builtin_amdgcn_mfma_f32_32x32x16_bf16(vf, pb, oc[dt], 0, 0, 0);
            }
        }
        __builtin_amdgcn_s_setprio(0);
    };

    const int NT = S / KVB;   // 64 (even)
    issue(); stageTo(Ks0, Vs0, mskf); issue();

    for (int it2 = 0; it2 < NT / 2; ++it2) {
        const int it = it2 * 2;
        __syncthreads();
        stageTo(Ks1, Vs1, mskf + KVB);
        if (it < NT - 2) issue();
        tile(Ks0, Vs0, mskf);
        __syncthreads();
        if (it + 1 < NT - 1) stageTo(Ks0, Vs0, mskf);
        if (it + 1 < NT - 2) issue();
        tile(Ks1, Vs1, mskf + KVB);
    }

    // ---- cross-wave (kw) reduction, then normalize + write
    __syncthreads();
    float* scr = (float*)sBuf;               // 2 q-groups x 64 lanes x 33 floats
    float* pp  = scr + (size_t)(qw * 64 + l) * 33;
    if (kw == 1) {
        #pragma unroll
        for (int r = 0; r < 16; ++r) { pp[r] = oc[0][r]; pp[16 + r] = oc[1][r]; }
        pp[32] = ls;
    }
    __syncthreads();
    if (kw == 0) {
        #pragma unroll
        for (int r = 0; r < 16; ++r) { oc[0][r] += pp[r]; oc[1][r] += pp[16 + r]; }
        ls += pp[32];
        ls += __shfl_xor(ls, 32);
        const float linv = 1.0f / ls;
        unsigned short* ap = (unsigned short*)att +
            ((size_t)(b * S + q0 + qw * 32 + l31)) * DM + h * DK;
        #pragma unroll
        for (int dt = 0; dt < 2; ++dt)
            #pragma unroll
            for (int g = 0; g < 4; ++g) {
                uint2 u;
                u.x = cvtpk(oc[dt][g * 4 + 0] * linv, oc[dt][g * 4 + 1] * linv);
                u.y = cvtpk(oc[dt][g * 4 + 2] * linv, oc[dt][g * 4 + 3] * linv);
                *(uint2*)(ap + dt * 32 + g * 8 + hi * 4) = u;
            }
    }
}

extern "C" void kernel_launch(void* const* d_in, const int* in_sizes, int n_in,
                              void* d_out, int out_size, void* d_ws, size_t ws_size,
                              hipStream_t stream) {
    const float* q    = (const float*)d_in[0];
    const float* k    = (const float*)d_in[1];
    const float* v    = (const float*)d_in[2];
    const int*   mask = (const int*)  d_in[3];
    const float* wq   = (const float*)d_in[4];
    const float* bq   = (const float*)d_in[5];
    const float* wk   = (const float*)d_in[6];
    const float* bk   = (const float*)d_in[7];
    const float* wv   = (const float*)d_in[8];
    const float* bv   = (const float*)d_in[9];
    const float* wo   = (const float*)d_in[10];
    const float* bo   = (const float*)d_in[11];
    float* out = (float*)d_out;

    char* wsb = (char*)d_ws;
    __hip_bfloat16* qh  = (__hip_bfloat16*)(wsb);
    __hip_bfloat16* kh  = (__hip_bfloat16*)(wsb + (size_t)8  * 1024 * 1024);
    __hip_bfloat16* vt  = (__hip_bfloat16*)(wsb + (size_t)16 * 1024 * 1024);
    __hip_bfloat16* att = (__hip_bfloat16*)(wsb + (size_t)24 * 1024 * 1024);

    dim3 blk(256);
    dim3 gq(24, MT / 128);                 // fused QKV: 1536 blocks
    qkv_gemm<<<gq, blk, 0, stream>>>(q, k, v, wq, wk, wv, bq, bk, bv,
                                     (unsigned short*)qh, (unsigned short*)kh,
                                     (unsigned short*)vt);

    dim3 g2(S / 64, 16);                   // 1024 blocks, 256 threads, 4 waves
    flash_mfma<<<g2, blk, 0, stream>>>(qh, kh, vt, mask, att);

    dim3 gg(DM / 64, MT / 128);            // (8, 64)
    out_gemm<<<gg, blk, 0, stream>>>((const short*)att, wo, bo, out);
}

// Round 11
// 166.719 us; speedup vs baseline: 1.3096x; 1.1730x over previous
//
#include <hip/hip_runtime.h>
#include <hip/hip_bf16.h>

#define S 4096
#define DM 512
#define HH 8
#define DK 64
#define MT 8192     // B*S
#define KVB 64

typedef __attribute__((ext_vector_type(8)))  short bf16x8;
typedef __attribute__((ext_vector_type(4)))  float f32x4;
typedef __attribute__((ext_vector_type(16))) float f32x16;
typedef __attribute__((ext_vector_type(4)))  unsigned int u32x4;

#define CQ 0.18033688011112042f   // 0.125 * log2(e), folded into Q projection

__device__ __forceinline__ short f2bs(float x) {
    __hip_bfloat16 h = __float2bfloat16(x);
    return *reinterpret_cast<short*>(&h);
}

__device__ __forceinline__ bf16x8 pack8(const float4& a, const float4& b) {
    bf16x8 r;
    r[0] = f2bs(a.x); r[1] = f2bs(a.y); r[2] = f2bs(a.z); r[3] = f2bs(a.w);
    r[4] = f2bs(b.x); r[5] = f2bs(b.y); r[6] = f2bs(b.z); r[7] = f2bs(b.w);
    return r;
}

__device__ __forceinline__ unsigned cvtpk(float lo, float hi) {
    unsigned r;
    asm("v_cvt_pk_bf16_f32 %0, %1, %2" : "=v"(r) : "v"(lo), "v"(hi));
    return r;
}

__device__ __forceinline__ bf16x8 mk_pb(unsigned a, unsigned b, unsigned c, unsigned d) {
    u32x4 t; t[0] = a; t[1] = b; t[2] = c; t[3] = d;
    return __builtin_bit_cast(bf16x8, t);
}

// ---------------- Fused QKV projection (XCD-swizzled grid) ----------------
// Flat grid 1536. HW XCD ~= bid % 8; work = (bid&7)*192 + bid>>3 gives each
// XCD a contiguous work chunk, and the 8 n-blocks sharing one X panel are
// consecutive works -> same XCD -> X panel fetched into L2 once, not 8x.
__global__ __launch_bounds__(256, 4)
void qkv_gemm(const float* __restrict__ Xq, const float* __restrict__ Xk,
              const float* __restrict__ Xv,
              const float* __restrict__ Wq, const float* __restrict__ Wk,
              const float* __restrict__ Wv,
              const float* __restrict__ Bq, const float* __restrict__ Bk,
              const float* __restrict__ Bv,
              unsigned short* __restrict__ Yq, unsigned short* __restrict__ Yk,
              unsigned short* __restrict__ Yv)
{
    __shared__ char As[128 * 128];
    __shared__ char Bs[64 * 128];
    const int bid  = blockIdx.x;
    const int work = (bid & 7) * 192 + (bid >> 3);
    const int gp   = work >> 3;            // 0..191 = (mat, m-panel)
    const int mat  = gp >> 6;
    const int m0   = (gp & 63) * 128;
    const int n0   = (work & 7) * 64;
    const float* X    = mat == 0 ? Xq : (mat == 1 ? Xk : Xv);
    const float* W    = mat == 0 ? Wq : (mat == 1 ? Wk : Wv);
    const float* bias = mat == 0 ? Bq : (mat == 1 ? Bk : Bv);

    const int t = threadIdx.x, l = t & 63, w = t >> 6;
    const int wr = w >> 1, wc = w & 1;
    const int lr = l & 15, lg = l >> 4;
    const int srow = t >> 3, schk = t & 7;
    const int sswz = (schk ^ (srow & 7)) * 16;

    float4 fA[4][2]; float4 fB[2][2];
    auto loadA = [&](int k0) {
        #pragma unroll
        for (int i = 0; i < 4; ++i) {
            const float* p = X + (size_t)(m0 + srow + 32 * i) * DM + k0 + schk * 8;
            fA[i][0] = *(const float4*)p;
            fA[i][1] = *(const float4*)(p + 4);
        }
    };
    auto loadB = [&](int k0) {
        #pragma unroll
        for (int i = 0; i < 2; ++i) {
            const float* p = W + (size_t)(n0 + srow + 32 * i) * DM + k0 + schk * 8;
            fB[i][0] = *(const float4*)p;
            fB[i][1] = *(const float4*)(p + 4);
        }
    };

    loadA(0); loadB(0);

    f32x4 acc[4][2];
    #pragma unroll
    for (int fm = 0; fm < 4; ++fm)
        #pragma unroll
        for (int fn = 0; fn < 2; ++fn) acc[fm][fn] = f32x4{0.f, 0.f, 0.f, 0.f};

    #pragma unroll
    for (int kt = 0; kt < 8; ++kt) {
        bf16x8 wA[4], wB[2];
        #pragma unroll
        for (int i = 0; i < 4; ++i) wA[i] = pack8(fA[i][0], fA[i][1]);
        #pragma unroll
        for (int i = 0; i < 2; ++i) wB[i] = pack8(fB[i][0], fB[i][1]);

        if (kt < 7) { loadA((kt + 1) * 64); loadB((kt + 1) * 64); }

        __syncthreads();
        #pragma unroll
        for (int i = 0; i < 4; ++i)
            *(bf16x8*)(As + (srow + 32 * i) * 128 + sswz) = wA[i];
        #pragma unroll
        for (int i = 0; i < 2; ++i)
            *(bf16x8*)(Bs + (srow + 32 * i) * 128 + sswz) = wB[i];
        __syncthreads();

        #pragma unroll
        for (int kc = 0; kc < 2; ++kc) {
            bf16x8 af[4], bfr[2];
            #pragma unroll
            for (int fm = 0; fm < 4; ++fm) {
                int row = wr * 64 + fm * 16 + lr;
                af[fm] = *(const bf16x8*)(As + row * 128 + (((kc * 4 + lg) ^ (row & 7)) * 16));
            }
            #pragma unroll
            for (int fn = 0; fn < 2; ++fn) {
                int row = wc * 32 + fn * 16 + lr;
                bfr[fn] = *(const bf16x8*)(Bs + row * 128 + (((kc * 4 + lg) ^ (row & 7)) * 16));
            }
            #pragma unroll
            for (int fm = 0; fm < 4; ++fm)
                #pragma unroll
                for (int fn = 0; fn < 2; ++fn)
                    acc[fm][fn] = __builtin_amdgcn_mfma_f32_16x16x32_bf16(af[fm], bfr[fn], acc[fm][fn], 0, 0, 0);
        }
    }

    const float scale = (mat == 0) ? CQ : 1.0f;
    #pragma unroll
    for (int fm = 0; fm < 4; ++fm) {
        #pragma unroll
        for (int fn = 0; fn < 2; ++fn) {
            int n = n0 + wc * 32 + fn * 16 + lr;
            float bn = bias[n];
            int mbase = m0 + wr * 64 + fm * 16 + lg * 4;
            int h = n >> 6, d = n & 63;
            if (mat < 2) {
                unsigned short* Y = (mat == 0) ? Yq : Yk;
                #pragma unroll
                for (int r = 0; r < 4; ++r) {
                    int m = mbase + r, b = m >> 12, s = m & (S - 1);
                    Y[(((size_t)(b * HH + h)) * S + s) * DK + d] =
                        (unsigned short)f2bs((acc[fm][fn][r] + bn) * scale);
                }
            } else {
                int b = mbase >> 12, s = mbase & (S - 1);
                ushort4 u;
                u.x = (unsigned short)f2bs(acc[fm][fn][0] + bn);
                u.y = (unsigned short)f2bs(acc[fm][fn][1] + bn);
                u.z = (unsigned short)f2bs(acc[fm][fn][2] + bn);
                u.w = (unsigned short)f2bs(acc[fm][fn][3] + bn);
                *(ushort4*)(Yv + ((size_t)((b * HH + h) * DK + d)) * S + s) = u;
            }
        }
    }
}

// ---------------- Output projection (XCD-swizzled grid) ----------------
// Flat grid 512. work = (bid&7)*64 + bid>>3: 8 n-blocks sharing an att
// panel are consecutive works -> one XCD.
__global__ __launch_bounds__(256, 2)
void out_gemm(const short* __restrict__ Xb, const float* __restrict__ W,
              const float* __restrict__ bias, float* __restrict__ Y)
{
    __shared__ char As[128 * 128];
    __shared__ char Bs[64 * 128];
    const int bid  = blockIdx.x;
    const int work = (bid & 7) * 64 + (bid >> 3);
    const int n0 = (work & 7) * 64;
    const int m0 = (work >> 3) * 128;

    const int t = threadIdx.x, l = t & 63, w = t >> 6;
    const int wr = w >> 1, wc = w & 1;
    const int lr = l & 15, lg = l >> 4;
    const int srow = t >> 3, schk = t & 7;
    const int sswz = (schk ^ (srow & 7)) * 16;

    float4 fB[2][2]; bf16x8 rA[4];
    auto loadA = [&](int k0) {
        #pragma unroll
        for (int i = 0; i < 4; ++i)
            rA[i] = *(const bf16x8*)(Xb + (size_t)(m0 + srow + 32 * i) * DM + k0 + schk * 8);
    };
    auto loadB = [&](int k0) {
        #pragma unroll
        for (int i = 0; i < 2; ++i) {
            const float* p = W + (size_t)(n0 + srow + 32 * i) * DM + k0 + schk * 8;
            fB[i][0] = *(const float4*)p;
            fB[i][1] = *(const float4*)(p + 4);
        }
    };

    loadA(0); loadB(0);

    f32x4 acc[4][2];
    #pragma unroll
    for (int fm = 0; fm < 4; ++fm)
        #pragma unroll
        for (int fn = 0; fn < 2; ++fn) acc[fm][fn] = f32x4{0.f, 0.f, 0.f, 0.f};

    #pragma unroll
    for (int kt = 0; kt < 8; ++kt) {
        bf16x8 wA[4], wB[2];
        #pragma unroll
        for (int i = 0; i < 4; ++i) wA[i] = rA[i];
        #pragma unroll
        for (int i = 0; i < 2; ++i) wB[i] = pack8(fB[i][0], fB[i][1]);

        if (kt < 7) { loadA((kt + 1) * 64); loadB((kt + 1) * 64); }

        __syncthreads();
        #pragma unroll
        for (int i = 0; i < 4; ++i)
            *(bf16x8*)(As + (srow + 32 * i) * 128 + sswz) = wA[i];
        #pragma unroll
        for (int i = 0; i < 2; ++i)
            *(bf16x8*)(Bs + (srow + 32 * i) * 128 + sswz) = wB[i];
        __syncthreads();

        #pragma unroll
        for (int kc = 0; kc < 2; ++kc) {
            bf16x8 af[4], bfr[2];
            #pragma unroll
            for (int fm = 0; fm < 4; ++fm) {
                int row = wr * 64 + fm * 16 + lr;
                af[fm] = *(const bf16x8*)(As + row * 128 + (((kc * 4 + lg) ^ (row & 7)) * 16));
            }
            #pragma unroll
            for (int fn = 0; fn < 2; ++fn) {
                int row = wc * 32 + fn * 16 + lr;
                bfr[fn] = *(const bf16x8*)(Bs + row * 128 + (((kc * 4 + lg) ^ (row & 7)) * 16));
            }
            #pragma unroll
            for (int fm = 0; fm < 4; ++fm)
                #pragma unroll
                for (int fn = 0; fn < 2; ++fn)
                    acc[fm][fn] = __builtin_amdgcn_mfma_f32_16x16x32_bf16(af[fm], bfr[fn], acc[fm][fn], 0, 0, 0);
        }
    }

    #pragma unroll
    for (int fm = 0; fm < 4; ++fm) {
        #pragma unroll
        for (int fn = 0; fn < 2; ++fn) {
            int n = n0 + wc * 32 + fn * 16 + lr;
            float bn = bias[n];
            int mbase = m0 + wr * 64 + fm * 16 + lg * 4;
            #pragma unroll
            for (int r = 0; r < 4; ++r)
                Y[(size_t)(mbase + r) * DM + n] = acc[fm][fn][r] + bn;
        }
    }
}

// ---------------- Flash attention (unchanged from R10) ---------------------
__global__ __launch_bounds__(256, 4)
void flash_mfma(const __hip_bfloat16* __restrict__ qh,
                const __hip_bfloat16* __restrict__ kh,
                const __hip_bfloat16* __restrict__ vt,
                const int* __restrict__ mask,
                __hip_bfloat16* __restrict__ att)
{
    const int bh = blockIdx.y, b = bh >> 3, h = bh & 7;
    const int q0 = blockIdx.x * 64;
    const int t = threadIdx.x, w = t >> 6, l = t & 63;
    const int l31 = l & 31, hi = l >> 5;
    const int kw = w & 1, qw = w >> 1;

    __shared__ char sBuf[32768 + 2 * KVB * 4];
    char* Ks0 = sBuf;
    char* Ks1 = sBuf + 8192;
    char* Vs0 = sBuf + 16384;
    char* Vs1 = sBuf + 24576;
    float* mskf = (float*)(sBuf + 32768);

    const short* qg = (const short*)qh + ((size_t)bh * S + q0 + qw * 32 + l31) * DK;
    bf16x8 qf[4];
    #pragma unroll
    for (int c = 0; c < 4; ++c)
        qf[c] = *(const bf16x8*)(qg + c * 16 + hi * 8);

    f32x16 oc[2];
    #pragma unroll
    for (int dt = 0; dt < 2; ++dt)
        #pragma unroll
        for (int r = 0; r < 16; ++r) oc[dt][r] = 0.f;
    float ls = 0.f;

    const int sr = t >> 2, c2 = (t & 3) * 2;
    const short* ksrc = (const short*)kh + (size_t)bh * S * DK + (size_t)sr * DK + c2 * 8;
    const short* vsrc = (const short*)vt + (size_t)bh * DK * S + (size_t)sr * S + c2 * 8;
    const int*   msrc = mask + b * S + (t & (KVB - 1));

    bf16x8 rK[2], rV[2];
    float  mreg = 0.f;

    auto issue = [&]() {
        rK[0] = *(const bf16x8*)(ksrc);
        rK[1] = *(const bf16x8*)(ksrc + 8);
        rV[0] = *(const bf16x8*)(vsrc);
        rV[1] = *(const bf16x8*)(vsrc + 8);
        if (t < KVB) mreg = msrc[0] ? 0.f : -3e38f;
        ksrc += KVB * DK; vsrc += KVB; msrc += KVB;
    };
    auto stageTo = [&](char* kb, char* vb, float* mf) {
        *(bf16x8*)(kb + sr * 128 + ((c2 ^ (sr & 7)) * 16))       = rK[0];
        *(bf16x8*)(kb + sr * 128 + (((c2 + 1) ^ (sr & 7)) * 16)) = rK[1];
        *(bf16x8*)(vb + sr * 128 + ((c2 ^ (sr & 7)) * 16))       = rV[0];
        *(bf16x8*)(vb + sr * 128 + (((c2 + 1) ^ (sr & 7)) * 16)) = rV[1];
        if (t < KVB) mf[t] = mreg;
    };

    const int kbase = kw * 32;
    const int kr    = kbase + l31;

    auto tile = [&](const char* kb, const char* vb, const float* mf) {
        f32x16 sc;
        #pragma unroll
        for (int g = 0; g < 4; ++g) {
            f32x4 m4 = *(const f32x4*)(mf + kbase + g * 8 + hi * 4);
            #pragma unroll
            for (int o = 0; o < 4; ++o) sc[g * 4 + o] = m4[o];
        }
        __builtin_amdgcn_s_setprio(1);
        #pragma unroll
        for (int c = 0; c < 4; ++c) {
            bf16x8 kf = *(const bf16x8*)(kb + kr * 128 + (((c * 2 + hi) ^ (kr & 7)) * 16));
            sc = __builtin_amdgcn_mfma_f32_32x32x16_bf16(kf, qf[c], sc, 0, 0, 0);
        }
        __builtin_amdgcn_s_setprio(0);

        float p[16];
        #pragma unroll
        for (int r = 0; r < 16; ++r) p[r] = exp2f(sc[r]);
        float a0 = 0.f;
        #pragma unroll
        for (int r = 0; r < 16; r += 4)
            a0 += (p[r] + p[r + 1]) + (p[r + 2] + p[r + 3]);
        ls += a0;

        unsigned A0 = cvtpk(p[0],  p[1]),  B0 = cvtpk(p[2],  p[3]);
        unsigned A1 = cvtpk(p[4],  p[5]),  B1 = cvtpk(p[6],  p[7]);
        unsigned A2 = cvtpk(p[8],  p[9]),  B2 = cvtpk(p[10], p[11]);
        unsigned A3 = cvtpk(p[12], p[13]), B3 = cvtpk(p[14], p[15]);
        asm("v_permlane32_swap_b32 %0, %1" : "+v"(A0), "+v"(A1));
        asm("v_permlane32_swap_b32 %0, %1" : "+v"(B0), "+v"(B1));
        asm("v_permlane32_swap_b32 %0, %1" : "+v"(A2), "+v"(A3));
        asm("v_permlane32_swap_b32 %0, %1" : "+v"(B2), "+v"(B3));
        bf16x8 pb0 = mk_pb(A0, B0, A1, B1);
        bf16x8 pb1 = mk_pb(A2, B2, A3, B3);

        __builtin_amdgcn_s_setprio(1);
        #pragma unroll
        for (int kcl = 0; kcl < 2; ++kcl) {
            const bf16x8 pb = kcl ? pb1 : pb0;
            #pragma unroll
            for (int dt = 0; dt < 2; ++dt) {
                const int vrow = dt * 32 + l31;
                bf16x8 vf = *(const bf16x8*)(vb + vrow * 128 +
                                (((kw * 4 + kcl * 2 + hi) ^ (vrow & 7)) * 16));
                oc[dt] = __builtin_amdgcn_mfma_f32_32x32x16_bf16(vf, pb, oc[dt], 0, 0, 0);
            }
        }
        __builtin_amdgcn_s_setprio(0);
    };

    const int NT = S / KVB;   // 64 (even)
    issue(); stageTo(Ks0, Vs0, mskf); issue();

    for (int it2 = 0; it2 < NT / 2; ++it2) {
        const int it = it2 * 2;
        __syncthreads();
        stageTo(Ks1, Vs1, mskf + KVB);
        if (it < NT - 2) issue();
        tile(Ks0, Vs0, mskf);
        __syncthreads();
        if (it + 1 < NT - 1) stageTo(Ks0, Vs0, mskf);
        if (it + 1 < NT - 2) issue();
        tile(Ks1, Vs1, mskf + KVB);
    }

    __syncthreads();
    float* scr = (float*)sBuf;
    float* pp  = scr + (size_t)(qw * 64 + l) * 33;
    if (kw == 1) {
        #pragma unroll
        for (int r = 0; r < 16; ++r) { pp[r] = oc[0][r]; pp[16 + r] = oc[1][r]; }
        pp[32] = ls;
    }
    __syncthreads();
    if (kw == 0) {
        #pragma unroll
        for (int r = 0; r < 16; ++r) { oc[0][r] += pp[r]; oc[1][r] += pp[16 + r]; }
        ls += pp[32];
        ls += __shfl_xor(ls, 32);
        const float linv = 1.0f / ls;
        unsigned short* ap = (unsigned short*)att +
            ((size_t)(b * S + q0 + qw * 32 + l31)) * DM + h * DK;
        #pragma unroll
        for (int dt = 0; dt < 2; ++dt)
            #pragma unroll
            for (int g = 0; g < 4; ++g) {
                uint2 u;
                u.x = cvtpk(oc[dt][g * 4 + 0] * linv, oc[dt][g * 4 + 1] * linv);
                u.y = cvtpk(oc[dt][g * 4 + 2] * linv, oc[dt][g * 4 + 3] * linv);
                *(uint2*)(ap + dt * 32 + g * 8 + hi * 4) = u;
            }
    }
}

extern "C" void kernel_launch(void* const* d_in, const int* in_sizes, int n_in,
                              void* d_out, int out_size, void* d_ws, size_t ws_size,
                              hipStream_t stream) {
    const float* q    = (const float*)d_in[0];
    const float* k    = (const float*)d_in[1];
    const float* v    = (const float*)d_in[2];
    const int*   mask = (const int*)  d_in[3];
    const float* wq   = (const float*)d_in[4];
    const float* bq   = (const float*)d_in[5];
    const float* wk   = (const float*)d_in[6];
    const float* bk   = (const float*)d_in[7];
    const float* wv   = (const float*)d_in[8];
    const float* bv   = (const float*)d_in[9];
    const float* wo   = (const float*)d_in[10];
    const float* bo   = (const float*)d_in[11];
    float* out = (float*)d_out;

    char* wsb = (char*)d_ws;
    __hip_bfloat16* qh  = (__hip_bfloat16*)(wsb);
    __hip_bfloat16* kh  = (__hip_bfloat16*)(wsb + (size_t)8  * 1024 * 1024);
    __hip_bfloat16* vt  = (__hip_bfloat16*)(wsb + (size_t)16 * 1024 * 1024);
    __hip_bfloat16* att = (__hip_bfloat16*)(wsb + (size_t)24 * 1024 * 1024);

    dim3 blk(256);
    qkv_gemm<<<dim3(1536), blk, 0, stream>>>(q, k, v, wq, wk, wv, bq, bk, bv,
                                     (unsigned short*)qh, (unsigned short*)kh,
                                     (unsigned short*)vt);

    dim3 g2(S / 64, 16);                   // 1024 blocks, 256 threads, 4 waves
    flash_mfma<<<g2, blk, 0, stream>>>(qh, kh, vt, mask, att);

    out_gemm<<<dim3(512), blk, 0, stream>>>((const short*)att, wo, bo, out);
}